// Round 9
// baseline (446.061 us; speedup 1.0000x reference)
//
#include <hip/hip_runtime.h>
#include <math.h>

#define BB 128
#define NN 128
#define DIN 1024
#define H1 256
#define DOUT 32
#define KCL 8
#define NPTS 128
#define MROWS (BB*NN)   // 16384
#define CSTR 130        // centsT row stride (words, init staging only)
#define RSTR 132        // cost/G row stride (words, 16B aligned)
#define HSTR 257        // mlp2 h-chunk row stride (odd -> conflict-free reads)
#define DEADKEY 0xFFFFFFFF00000000ull

__device__ __forceinline__ float gelu_exact(float v) {
    return 0.5f * v * (1.0f + erff(v * 0.70710678118654752f));
}

__device__ __forceinline__ unsigned long long mkkey(float v, int r, int j) {
    return ((unsigned long long)__float_as_uint(v) << 32) | (unsigned)((r << 7) | j);
}

__device__ __forceinline__ float readlanef(float v, int lane) {
    return __int_as_float(__builtin_amdgcn_readlane(__float_as_int(v), lane));
}

// u32 min via DPP (costs are >=0 floats: IEEE order == unsigned bit order)
template<int CTRL, int RMASK>
__device__ __forceinline__ unsigned dpp_umin_step(unsigned v) {
    unsigned t = (unsigned)__builtin_amdgcn_update_dpp((int)v, (int)v, CTRL, RMASK, 0xf, false);
    return t < v ? t : v;
}
__device__ __forceinline__ unsigned wave_umin_bcast(unsigned v) {
    v = dpp_umin_step<0x111, 0xf>(v);
    v = dpp_umin_step<0x112, 0xf>(v);
    v = dpp_umin_step<0x114, 0xf>(v);
    v = dpp_umin_step<0x118, 0xf>(v);
    v = dpp_umin_step<0x142, 0xa>(v);
    v = dpp_umin_step<0x143, 0xc>(v);
    return (unsigned)__builtin_amdgcn_readlane((int)v, 63);
}
// lane31 = min(lanes0..31), lane63 = min(lanes32..63)
__device__ __forceinline__ unsigned half_umin(unsigned v) {
    v = dpp_umin_step<0x111, 0xf>(v);
    v = dpp_umin_step<0x112, 0xf>(v);
    v = dpp_umin_step<0x114, 0xf>(v);
    v = dpp_umin_step<0x118, 0xf>(v);
    v = dpp_umin_step<0x142, 0xa>(v);
    return v;
}

// ---------------- gelu precompute: gx = gelu(x), memory-bound ----------------
__global__ __launch_bounds__(256) void gelu_kernel(const float* __restrict__ x,
                                                   float* __restrict__ gx, int n4) {
    int i = blockIdx.x * 256 + threadIdx.x;
    const int stride = gridDim.x * 256;
    for (; i < n4; i += stride) {
        float4 v = ((const float4*)x)[i];
        v.x = gelu_exact(v.x);
        v.y = gelu_exact(v.y);
        v.z = gelu_exact(v.z);
        v.w = gelu_exact(v.w);
        ((float4*)gx)[i] = v;
    }
}

// ---------------- GEMM1: h = A @ W1 + b1 ----------------
// 64x64 tile, 4x4 microtile, BK=64 (R8 base). B-tile staged via global_load_lds
// width=16 (Bs stride 64 -> lane-linear dest; 4 ops/wave/K-step replace 8 staging
// instrs/thread). A stays VGPR-staged (needs transpose + optional gelu).
// k-ascending FMA order preserved -> h bit-identical.
template<bool FUSE>
__global__ __launch_bounds__(256) void mlp1_kernel(const float* __restrict__ xin,
                                                   const float* __restrict__ W1,
                                                   const float* __restrict__ b1,
                                                   float* __restrict__ h) {
    __shared__ float As[64][68];  // [k][m] 17.4 KB
    __shared__ float Bs[64][64];  // [k][n] 16.0 KB (lane-linear for global_load_lds)
    const int bn = blockIdx.x;    // 4 col-tiles of 64
    const int bm = blockIdx.y;    // 256 row-tiles of 64
    const int tid = threadIdx.x;
    const int tx = tid & 15, ty = tid >> 4;

    float acc[4][4] = {{0.f}};

    const int arow = tid >> 2;         // 0..63
    const int kc   = (tid & 3) * 4;    // k offset 0,4,8,12 (within each 16-group)
    const int wv   = tid >> 6;         // wave 0..3
    const int ln   = tid & 63;
    const int bkr  = ln >> 4;          // 0..3 (row within 4-row group)
    const int bkc  = (ln & 15) * 4;    // 0..60

    const float* xrow = xin + (size_t)(bm * 64 + arow) * DIN;
    const float* wbase = W1 + bn * 64;

    for (int kt = 0; kt < DIN; kt += 64) {
        float4 a0 = *(const float4*)(xrow + kt + kc);
        float4 a1 = *(const float4*)(xrow + kt + kc + 16);
        float4 a2 = *(const float4*)(xrow + kt + kc + 32);
        float4 a3 = *(const float4*)(xrow + kt + kc + 48);
        __syncthreads();
        // B: each wave fills its 16 k-rows via 4 global_load_lds (16B/lane, lane-linear)
#pragma unroll
        for (int s = 0; s < 4; ++s) {
            const int kr = wv * 16 + s * 4;
            const float* g = wbase + (size_t)(kt + kr + bkr) * H1 + bkc;
            __builtin_amdgcn_global_load_lds(
                (const __attribute__((address_space(1))) unsigned int*)g,
                (__attribute__((address_space(3))) unsigned int*)&Bs[kr][0], 16, 0, 0);
        }
        if (FUSE) {
            As[kc + 0][arow] = gelu_exact(a0.x);
            As[kc + 1][arow] = gelu_exact(a0.y);
            As[kc + 2][arow] = gelu_exact(a0.z);
            As[kc + 3][arow] = gelu_exact(a0.w);
            As[16 + kc + 0][arow] = gelu_exact(a1.x);
            As[16 + kc + 1][arow] = gelu_exact(a1.y);
            As[16 + kc + 2][arow] = gelu_exact(a1.z);
            As[16 + kc + 3][arow] = gelu_exact(a1.w);
            As[32 + kc + 0][arow] = gelu_exact(a2.x);
            As[32 + kc + 1][arow] = gelu_exact(a2.y);
            As[32 + kc + 2][arow] = gelu_exact(a2.z);
            As[32 + kc + 3][arow] = gelu_exact(a2.w);
            As[48 + kc + 0][arow] = gelu_exact(a3.x);
            As[48 + kc + 1][arow] = gelu_exact(a3.y);
            As[48 + kc + 2][arow] = gelu_exact(a3.z);
            As[48 + kc + 3][arow] = gelu_exact(a3.w);
        } else {
            As[kc + 0][arow] = a0.x;
            As[kc + 1][arow] = a0.y;
            As[kc + 2][arow] = a0.z;
            As[kc + 3][arow] = a0.w;
            As[16 + kc + 0][arow] = a1.x;
            As[16 + kc + 1][arow] = a1.y;
            As[16 + kc + 2][arow] = a1.z;
            As[16 + kc + 3][arow] = a1.w;
            As[32 + kc + 0][arow] = a2.x;
            As[32 + kc + 1][arow] = a2.y;
            As[32 + kc + 2][arow] = a2.z;
            As[32 + kc + 3][arow] = a2.w;
            As[48 + kc + 0][arow] = a3.x;
            As[48 + kc + 1][arow] = a3.y;
            As[48 + kc + 2][arow] = a3.z;
            As[48 + kc + 3][arow] = a3.w;
        }
        __syncthreads();  // drains vmcnt (incl. global_load_lds) + lgkmcnt
#pragma unroll
        for (int kk = 0; kk < 64; ++kk) {
            float4 a = *(const float4*)&As[kk][ty * 4];
            float4 b = *(const float4*)&Bs[kk][tx * 4];
            float ar[4] = {a.x, a.y, a.z, a.w};
            float br[4] = {b.x, b.y, b.z, b.w};
#pragma unroll
            for (int i = 0; i < 4; ++i)
#pragma unroll
                for (int j = 0; j < 4; ++j)
                    acc[i][j] = fmaf(ar[i], br[j], acc[i][j]);
        }
    }

    const int row = bm * 64 + ty * 4;
    const int col = bn * 64 + tx * 4;
    float4 bias = *(const float4*)(b1 + col);
#pragma unroll
    for (int i = 0; i < 4; ++i) {
        float4 o;
        o.x = acc[i][0] + bias.x;
        o.y = acc[i][1] + bias.y;
        o.z = acc[i][2] + bias.z;
        o.w = acc[i][3] + bias.w;
        *(float4*)(h + (size_t)(row + i) * H1 + col) = o;
    }
}

// ---------------- GEMM2: feats = gelu(h) @ W2 + b2 (R7 version, verified) ----------------
__global__ __launch_bounds__(256) void mlp2_kernel(const float* __restrict__ h,
                                                   const float* __restrict__ W2,
                                                   const float* __restrict__ b2,
                                                   float* __restrict__ feats) {
    __shared__ float hs[32 * HSTR];    // 32.9 KB
    __shared__ float w2s[H1 * DOUT];   // 32 KB
    const int blk = blockIdx.x;
    const int tid = threadIdx.x;

    for (int i = tid; i < (H1 * DOUT) / 4; i += 256)
        ((float4*)w2s)[i] = ((const float4*)W2)[i];

    const float* hb = h + (size_t)blk * 32 * H1;
    const int sr = tid & 31;          // staging row 0..31
    const int sk = (tid >> 5) * 32;   // staging k-base (8 groups of 32)
    const float* hrow = hb + (size_t)sr * H1 + sk;
#pragma unroll
    for (int j = 0; j < 8; ++j) {
        float4 v = ((const float4*)hrow)[j];
        hs[sr * HSTR + sk + 4 * j + 0] = gelu_exact(v.x);
        hs[sr * HSTR + sk + 4 * j + 1] = gelu_exact(v.y);
        hs[sr * HSTR + sk + 4 * j + 2] = gelu_exact(v.z);
        hs[sr * HSTR + sk + 4 * j + 3] = gelu_exact(v.w);
    }
    __syncthreads();

    const int row = tid >> 3;         // 0..31
    const int col4 = (tid & 7) * 4;   // 0,4,..,28
    const float4 bias = ((const float4*)b2)[tid & 7];
    float a0 = 0.f, a1 = 0.f, a2 = 0.f, a3 = 0.f;
    const float* hr = &hs[row * HSTR];
    for (int k = 0; k < H1; ++k) {
        float a = hr[k];
        float4 w = *(const float4*)&w2s[k * DOUT + col4];
        a0 = fmaf(a, w.x, a0);
        a1 = fmaf(a, w.y, a1);
        a2 = fmaf(a, w.z, a2);
        a3 = fmaf(a, w.w, a3);
    }
    float4 o;
    o.x = a0 + bias.x;
    o.y = a1 + bias.y;
    o.z = a2 + bias.z;
    o.w = a3 + bias.w;
    *(float4*)(feats + (size_t)(blk * 32 + row) * DOUT + col4) = o;
}

// ---------------- Ward clustering: incremental Gram + quad-rotated cost/G columns ----------------
// Column addressing: physical col PC(r,c) = (c + 4*((r>>1)&31)) & 127. Pure bijective
// per-row quad rotation -> values bit-identical. Converts the 4 per-iteration column
// writes (G[r0][i2], G[r1][i2], cost[r0][i2], cost[r1][i2]) from 16-way to 8-way bank
// conflicts (banks 12*lane+i2: 8 distinct vs 8*lane+i2: 4 distinct). Row-contiguous
// reads (float2 G, b128 rescan) remain conflict-free; rescan converts physical quad ->
// logical column for keys and the alive mask.
__global__ __launch_bounds__(256) void ward_kernel(const float* __restrict__ feats,
                                                   int* __restrict__ out) {
    __shared__ __align__(16) float cost[NPTS * RSTR];  // 67.6 KB
    __shared__ __align__(16) float G[NPTS * RSTR];     // 67.6 KB Gram matrix
    __shared__ float centsT[32 * CSTR];                // init staging only
    __shared__ unsigned long long rowkey[NPTS];
    __shared__ float sqArr[NPTS];
    __shared__ float szsE[NPTS];
    __shared__ int rnk[NPTS];

    const int b = blockIdx.x;
    const int tid = threadIdx.x;
    const float* f = feats + (size_t)b * NPTS * DOUT;
    const float INF = __builtin_inff();

    // ---- init (all 4 waves) ----
    for (int i = tid; i < NPTS * DOUT; i += 256) {
        int r = i >> 5, d = i & 31;
        centsT[d * CSTR + r] = f[i];
    }
    __syncthreads();
    if (tid < NPTS) {
        float s = 0.f;
#pragma unroll
        for (int d = 0; d < 32; ++d) {
            float v = centsT[d * CSTR + tid];
            s = fmaf(v, v, s);
        }
        sqArr[tid] = s;
    }
    __syncthreads();
    {
        int ti = tid >> 4, tj = tid & 15;
        int I0 = ti * 8, J0 = tj * 8;
        float acc[8][8];
#pragma unroll
        for (int u = 0; u < 8; ++u)
#pragma unroll
            for (int v = 0; v < 8; ++v) acc[u][v] = 0.f;
        for (int d = 0; d < 32; ++d) {
            float a[8], bb[8];
#pragma unroll
            for (int u = 0; u < 8; ++u) a[u] = centsT[d * CSTR + I0 + u];
#pragma unroll
            for (int v = 0; v < 8; ++v) bb[v] = centsT[d * CSTR + J0 + v];
#pragma unroll
            for (int u = 0; u < 8; ++u)
#pragma unroll
                for (int v = 0; v < 8; ++v)
                    acc[u][v] = fmaf(a[u], bb[v], acc[u][v]);
        }
#pragma unroll
        for (int u = 0; u < 8; ++u) {
            const int i = I0 + u;
            const int rq = 4 * ((i >> 1) & 31);
#pragma unroll
            for (int v = 0; v < 8; ++v) {
                int j = J0 + v;
                int pc = (j + rq) & 127;
                G[i * RSTR + pc] = acc[u][v];
                float d2 = sqArr[i] + sqArr[j] - 2.0f * acc[u][v];
                if (d2 < 0.f) d2 = 0.f;
                float w = (1.0f * 1.0f) / (1.0f + 1.0f + 1e-30f);
                cost[i * RSTR + pc] = (i == j) ? INF : w * d2;
            }
        }
    }
    __syncthreads();
    if (tid < NPTS) {
        unsigned long long best = DEADKEY;
        const int rq = 4 * ((tid >> 1) & 31);
        for (int j = 0; j < NPTS; ++j) {
            float v = cost[tid * RSTR + ((j + rq) & 127)];
            unsigned long long k = mkkey(v, tid, j);
            if (k < best) best = k;
        }
        rowkey[tid] = best;
    }
    __syncthreads();

    if (tid >= 64) return;  // wave 0 only
    const int lane = tid;
    const int hh = lane & 31;
    const int r0 = lane * 2, r1 = lane * 2 + 1;
    const int hq4 = 4 * hh;  // rotation for this lane's rows (r0>>1 == r1>>1 == lane)

    unsigned long long k0 = rowkey[r0], k1 = rowkey[r1];
    float q0 = sqArr[r0], q1 = sqArr[r1];
    float s0 = 1.0f, s1 = 1.0f;
    int lab0 = r0, lab1 = r1;
    unsigned long long alive0 = ~0ull, alive1 = ~0ull;

    for (int it = 0; it < NPTS - KCL; ++it) {
        // P1: global argmin via u32-bits DPP min + ballot (exact flat-index tie-break)
        unsigned bv0 = (unsigned)(k0 >> 32), bv1 = (unsigned)(k1 >> 32);
        unsigned lmin = bv0 < bv1 ? bv0 : bv1;
        unsigned lflat = (bv0 <= bv1) ? (unsigned)(k0 & 0x3FFFu) : (unsigned)(k1 & 0x3FFFu);
        unsigned gmin = wave_umin_bcast(lmin);
        unsigned long long bmask = __ballot(lmin == gmin);
        int lsel = __ffsll(bmask) - 1;
        unsigned flat = (unsigned)__builtin_amdgcn_readlane((int)lflat, lsel);
        int ra = (int)(flat >> 7), ca = (int)(flat & 127u);
        const int i2 = ra < ca ? ra : ca;
        const int j2 = ra < ca ? ca : ra;
        const int ri2 = 4 * ((i2 >> 1) & 31);
        const int rj2 = 4 * ((j2 >> 1) & 31);

        // Gram rows i2, j2 (issued early; only depend on i2/j2)
        float2 gi = *(const float2*)&G[i2 * RSTR + ((r0 + ri2) & 127)];
        float2 gj = *(const float2*)&G[j2 * RSTR + ((r0 + rj2) & 127)];

        float si = readlanef((i2 & 1) ? s1 : s0, i2 >> 1);
        float sj = readlanef((j2 & 1) ? s1 : s0, j2 >> 1);
        const float snew = si + sj;
        const float invs = 1.0f / snew;
        const float wa = si * invs, wb = sj * invs;

        int arg0 = (int)(k0 & 127u), arg1 = (int)(k1 & 127u);
        bool d0 = (s0 > 0.f) && r0 != i2 && r0 != j2 && (arg0 == i2 || arg0 == j2);
        bool d1 = (s1 > 0.f) && r1 != i2 && r1 != j2 && (arg1 == i2 || arg1 == j2);
        unsigned long long m0 = __ballot(d0), m1 = __ballot(d1);

        // scalar Gram entries for qn
        float Gii = readlanef((i2 & 1) ? gi.y : gi.x, i2 >> 1);
        float Gij = readlanef((i2 & 1) ? gj.y : gj.x, i2 >> 1);
        float Gjj = readlanef((j2 & 1) ? gj.y : gj.x, j2 >> 1);
        float dotA = wa * Gii + wb * Gij;
        float dotB = wa * Gij + wb * Gjj;
        float qn = wa * dotA + wb * dotB;

        // per-lane dots with merged cluster (linear Gram update)
        float dot0 = wa * gi.x + wb * gj.x;
        float dot1 = wa * gi.y + wb * gj.y;

        // state updates
        if (lab0 == j2) lab0 = i2;
        if (lab1 == j2) lab1 = i2;
        if (r0 == i2) s0 = snew; else if (r0 == j2) { s0 = 0.f; k0 = DEADKEY; }
        if (r1 == i2) s1 = snew; else if (r1 == j2) { s1 = 0.f; k1 = DEADKEY; }
        if (j2 < 64) alive0 &= ~(1ull << j2); else alive1 &= ~(1ull << (j2 - 64));
        if (r0 == i2) { dot0 = qn; q0 = qn; }
        if (r1 == i2) { dot1 = qn; q1 = qn; }

        // G updates: row i2 (contiguous b64), column i2 (8-way after rotation)
        *(float2*)&G[i2 * RSTR + ((r0 + ri2) & 127)] = make_float2(dot0, dot1);
        G[r0 * RSTR + ((i2 + hq4) & 127)] = dot0;
        G[r1 * RSTR + ((i2 + hq4) & 127)] = dot1;

        // cost values for row/col i2
        bool w0 = (s0 > 0.f) && r0 != i2 && r0 != j2;
        bool w1 = (s1 > 0.f) && r1 != i2 && r1 != j2;
        if (w0) {
            float d2 = q0 + qn - 2.0f * dot0;
            if (d2 < 0.f) d2 = 0.f;
            float w = (s0 * snew) / (s0 + snew + 1e-30f);
            float v0 = w * d2;
            cost[r0 * RSTR + ((i2 + hq4) & 127)] = v0;
            cost[i2 * RSTR + ((r0 + ri2) & 127)] = v0;
            if (!d0) {
                unsigned long long nk = mkkey(v0, r0, i2);
                if (nk < k0) k0 = nk;
            }
        }
        if (w1) {
            float d2 = q1 + qn - 2.0f * dot1;
            if (d2 < 0.f) d2 = 0.f;
            float w = (s1 * snew) / (s1 + snew + 1e-30f);
            float v1 = w * d2;
            cost[r1 * RSTR + ((i2 + hq4) & 127)] = v1;
            cost[i2 * RSTR + ((r1 + ri2) & 127)] = v1;
            if (!d1) {
                unsigned long long nk = mkkey(v1, r1, i2);
                if (nk < k1) k1 = nk;
            }
        }

        // rescans: row i2 (always) + dirty rows; 2 rows/round, b128 physical traversal
        bool pi = true;
        unsigned long long mm0 = m0, mm1 = m1;
        while (pi | (mm0 != 0ull) | (mm1 != 0ull)) {
            int rA, rB;
            bool hasB = false;
            if (pi) { rA = i2; pi = false; }
            else if (mm0) { int t = __ffsll(mm0) - 1; rA = 2 * t; mm0 &= mm0 - 1; }
            else { int t = __ffsll(mm1) - 1; rA = 2 * t + 1; mm1 &= mm1 - 1; }
            if (mm0) { int t = __ffsll(mm0) - 1; rB = 2 * t; mm0 &= mm0 - 1; hasB = true; }
            else if (mm1) { int t = __ffsll(mm1) - 1; rB = 2 * t + 1; mm1 &= mm1 - 1; hasB = true; }
            else rB = rA;

            int r = (lane < 32) ? rA : rB;
            float4 cv = *(const float4*)&cost[r * RSTR + 4 * hh];
            int lq = (hh - ((r >> 1) & 31)) & 31;  // logical quad held by this lane
            unsigned long long word = (lq < 16) ? alive0 : alive1;
            unsigned nib = (unsigned)(word >> ((4 * lq) & 63)) & 0xFu;
            unsigned e0 = (nib & 1u) ? __float_as_uint(cv.x) : 0xFFFFFFFFu;
            unsigned e1 = (nib & 2u) ? __float_as_uint(cv.y) : 0xFFFFFFFFu;
            unsigned e2 = (nib & 4u) ? __float_as_uint(cv.z) : 0xFFFFFFFFu;
            unsigned e3 = (nib & 8u) ? __float_as_uint(cv.w) : 0xFFFFFFFFu;
            unsigned m = e0; int c = 0;
            if (e1 < m) { m = e1; c = 1; }
            if (e2 < m) { m = e2; c = 2; }
            if (e3 < m) { m = e3; c = 3; }
            int lcol = 4 * lq + c;
            unsigned hm = half_umin(m);
            unsigned vA = (unsigned)__builtin_amdgcn_readlane((int)hm, 31);
            unsigned vB = (unsigned)__builtin_amdgcn_readlane((int)hm, 63);
            unsigned vref = (lane < 32) ? vA : vB;
            unsigned long long msk = __ballot(m == vref);
            int laneA = __ffsll(msk & 0xFFFFFFFFull) - 1;
            int laneB = 32 + __ffsll(msk >> 32) - 1;
            int colA = __builtin_amdgcn_readlane(lcol, laneA);
            int colB = __builtin_amdgcn_readlane(lcol, laneB);
            unsigned long long keyA = ((unsigned long long)vA << 32) | (unsigned)((rA << 7) | colA);
            unsigned long long keyB = ((unsigned long long)vB << 32) | (unsigned)((rB << 7) | colB);
            if (lane == (rA >> 1)) { if (rA & 1) k1 = keyA; else k0 = keyA; }
            if (hasB && lane == (rB >> 1)) { if (rB & 1) k1 = keyB; else k0 = keyB; }
        }
    }

    // final relabel
    szsE[r0] = s0;
    szsE[r1] = s1;
    __asm__ volatile("s_waitcnt lgkmcnt(0)" ::: "memory");
    if (lane == 0) {
        int c = 0;
        for (int i = 0; i < NPTS; ++i) rnk[i] = (szsE[i] > 0.f) ? c++ : -1;
    }
    __asm__ volatile("s_waitcnt lgkmcnt(0)" ::: "memory");
    out[b * NPTS + r0] = rnk[lab0];
    out[b * NPTS + r1] = rnk[lab1];
}

extern "C" void kernel_launch(void* const* d_in, const int* in_sizes, int n_in,
                              void* d_out, int out_size, void* d_ws, size_t ws_size,
                              hipStream_t stream) {
    const float* x  = (const float*)d_in[0];
    const float* W1 = (const float*)d_in[1];
    const float* b1 = (const float*)d_in[2];
    const float* W2 = (const float*)d_in[3];
    const float* b2 = (const float*)d_in[4];

    float* h = (float*)d_ws;                          // 16 MB
    float* feats = h + (size_t)MROWS * H1;            // 2 MB
    float* gx = feats + (size_t)MROWS * DOUT;         // 64 MB (if it fits)
    int* out = (int*)d_out;

    const size_t need = ((size_t)MROWS * H1 + (size_t)MROWS * DOUT + (size_t)MROWS * DIN) * 4;
    const bool use_gx = ws_size >= need;

    if (use_gx) {
        gelu_kernel<<<2048, 256, 0, stream>>>(x, gx, MROWS * DIN / 4);
        mlp1_kernel<false><<<dim3(H1 / 64, MROWS / 64), 256, 0, stream>>>(gx, W1, b1, h);
    } else {
        mlp1_kernel<true><<<dim3(H1 / 64, MROWS / 64), 256, 0, stream>>>(x, W1, b1, h);
    }
    mlp2_kernel<<<MROWS / 32, 256, 0, stream>>>(h, W2, b2, feats);
    ward_kernel<<<BB, 256, 0, stream>>>(feats, out);
}

// Round 10
// 431.854 us; speedup vs baseline: 1.0329x; 1.0329x over previous
//
#include <hip/hip_runtime.h>
#include <math.h>

#define BB 128
#define NN 128
#define DIN 1024
#define H1 256
#define DOUT 32
#define KCL 8
#define NPTS 128
#define MROWS (BB*NN)   // 16384
#define CSTR 130        // centsT row stride (words, init staging only)
#define RSTR 132        // cost row stride (words, 16B aligned)
#define HSTR 257        // mlp2 h-chunk row stride (odd -> conflict-free reads)
#define DEADKEY 0xFFFFFFFF00000000ull

__device__ __forceinline__ float gelu_exact(float v) {
    return 0.5f * v * (1.0f + erff(v * 0.70710678118654752f));
}

__device__ __forceinline__ unsigned long long mkkey(float v, int r, int j) {
    return ((unsigned long long)__float_as_uint(v) << 32) | (unsigned)((r << 7) | j);
}

__device__ __forceinline__ float readlanef(float v, int lane) {
    return __int_as_float(__builtin_amdgcn_readlane(__float_as_int(v), lane));
}

// u32 min via DPP (costs are >=0 floats: IEEE order == unsigned bit order)
template<int CTRL, int RMASK>
__device__ __forceinline__ unsigned dpp_umin_step(unsigned v) {
    unsigned t = (unsigned)__builtin_amdgcn_update_dpp((int)v, (int)v, CTRL, RMASK, 0xf, false);
    return t < v ? t : v;
}
__device__ __forceinline__ unsigned wave_umin_bcast(unsigned v) {
    v = dpp_umin_step<0x111, 0xf>(v);
    v = dpp_umin_step<0x112, 0xf>(v);
    v = dpp_umin_step<0x114, 0xf>(v);
    v = dpp_umin_step<0x118, 0xf>(v);
    v = dpp_umin_step<0x142, 0xa>(v);
    v = dpp_umin_step<0x143, 0xc>(v);
    return (unsigned)__builtin_amdgcn_readlane((int)v, 63);
}
// lane31 = min(lanes0..31), lane63 = min(lanes32..63)
__device__ __forceinline__ unsigned half_umin(unsigned v) {
    v = dpp_umin_step<0x111, 0xf>(v);
    v = dpp_umin_step<0x112, 0xf>(v);
    v = dpp_umin_step<0x114, 0xf>(v);
    v = dpp_umin_step<0x118, 0xf>(v);
    v = dpp_umin_step<0x142, 0xa>(v);
    return v;
}

// ---------------- gelu precompute: gx = gelu(x), memory-bound ----------------
__global__ __launch_bounds__(256) void gelu_kernel(const float* __restrict__ x,
                                                   float* __restrict__ gx, int n4) {
    int i = blockIdx.x * 256 + threadIdx.x;
    const int stride = gridDim.x * 256;
    for (; i < n4; i += stride) {
        float4 v = ((const float4*)x)[i];
        v.x = gelu_exact(v.x);
        v.y = gelu_exact(v.y);
        v.z = gelu_exact(v.z);
        v.w = gelu_exact(v.w);
        ((float4*)gx)[i] = v;
    }
}

// ---------------- GEMM1: h = A @ W1 + b1 ----------------
// 64x64 tile, 4x4 microtile, BK=64, B staged via global_load_lds width=16 (R9 version,
// verified bit-exact). A stays VGPR-staged (transpose + optional gelu).
template<bool FUSE>
__global__ __launch_bounds__(256) void mlp1_kernel(const float* __restrict__ xin,
                                                   const float* __restrict__ W1,
                                                   const float* __restrict__ b1,
                                                   float* __restrict__ h) {
    __shared__ float As[64][68];  // [k][m] 17.4 KB
    __shared__ float Bs[64][64];  // [k][n] 16.0 KB (lane-linear for global_load_lds)
    const int bn = blockIdx.x;    // 4 col-tiles of 64
    const int bm = blockIdx.y;    // 256 row-tiles of 64
    const int tid = threadIdx.x;
    const int tx = tid & 15, ty = tid >> 4;

    float acc[4][4] = {{0.f}};

    const int arow = tid >> 2;         // 0..63
    const int kc   = (tid & 3) * 4;    // k offset 0,4,8,12 (within each 16-group)
    const int wv   = tid >> 6;         // wave 0..3
    const int ln   = tid & 63;
    const int bkr  = ln >> 4;          // 0..3 (row within 4-row group)
    const int bkc  = (ln & 15) * 4;    // 0..60

    const float* xrow = xin + (size_t)(bm * 64 + arow) * DIN;
    const float* wbase = W1 + bn * 64;

    for (int kt = 0; kt < DIN; kt += 64) {
        float4 a0 = *(const float4*)(xrow + kt + kc);
        float4 a1 = *(const float4*)(xrow + kt + kc + 16);
        float4 a2 = *(const float4*)(xrow + kt + kc + 32);
        float4 a3 = *(const float4*)(xrow + kt + kc + 48);
        __syncthreads();
        // B: each wave fills its 16 k-rows via 4 global_load_lds (16B/lane, lane-linear)
#pragma unroll
        for (int s = 0; s < 4; ++s) {
            const int kr = wv * 16 + s * 4;
            const float* g = wbase + (size_t)(kt + kr + bkr) * H1 + bkc;
            __builtin_amdgcn_global_load_lds(
                (const __attribute__((address_space(1))) unsigned int*)g,
                (__attribute__((address_space(3))) unsigned int*)&Bs[kr][0], 16, 0, 0);
        }
        if (FUSE) {
            As[kc + 0][arow] = gelu_exact(a0.x);
            As[kc + 1][arow] = gelu_exact(a0.y);
            As[kc + 2][arow] = gelu_exact(a0.z);
            As[kc + 3][arow] = gelu_exact(a0.w);
            As[16 + kc + 0][arow] = gelu_exact(a1.x);
            As[16 + kc + 1][arow] = gelu_exact(a1.y);
            As[16 + kc + 2][arow] = gelu_exact(a1.z);
            As[16 + kc + 3][arow] = gelu_exact(a1.w);
            As[32 + kc + 0][arow] = gelu_exact(a2.x);
            As[32 + kc + 1][arow] = gelu_exact(a2.y);
            As[32 + kc + 2][arow] = gelu_exact(a2.z);
            As[32 + kc + 3][arow] = gelu_exact(a2.w);
            As[48 + kc + 0][arow] = gelu_exact(a3.x);
            As[48 + kc + 1][arow] = gelu_exact(a3.y);
            As[48 + kc + 2][arow] = gelu_exact(a3.z);
            As[48 + kc + 3][arow] = gelu_exact(a3.w);
        } else {
            As[kc + 0][arow] = a0.x;
            As[kc + 1][arow] = a0.y;
            As[kc + 2][arow] = a0.z;
            As[kc + 3][arow] = a0.w;
            As[16 + kc + 0][arow] = a1.x;
            As[16 + kc + 1][arow] = a1.y;
            As[16 + kc + 2][arow] = a1.z;
            As[16 + kc + 3][arow] = a1.w;
            As[32 + kc + 0][arow] = a2.x;
            As[32 + kc + 1][arow] = a2.y;
            As[32 + kc + 2][arow] = a2.z;
            As[32 + kc + 3][arow] = a2.w;
            As[48 + kc + 0][arow] = a3.x;
            As[48 + kc + 1][arow] = a3.y;
            As[48 + kc + 2][arow] = a3.z;
            As[48 + kc + 3][arow] = a3.w;
        }
        __syncthreads();  // drains vmcnt (incl. global_load_lds) + lgkmcnt
#pragma unroll
        for (int kk = 0; kk < 64; ++kk) {
            float4 a = *(const float4*)&As[kk][ty * 4];
            float4 b = *(const float4*)&Bs[kk][tx * 4];
            float ar[4] = {a.x, a.y, a.z, a.w};
            float br[4] = {b.x, b.y, b.z, b.w};
#pragma unroll
            for (int i = 0; i < 4; ++i)
#pragma unroll
                for (int j = 0; j < 4; ++j)
                    acc[i][j] = fmaf(ar[i], br[j], acc[i][j]);
        }
    }

    const int row = bm * 64 + ty * 4;
    const int col = bn * 64 + tx * 4;
    float4 bias = *(const float4*)(b1 + col);
#pragma unroll
    for (int i = 0; i < 4; ++i) {
        float4 o;
        o.x = acc[i][0] + bias.x;
        o.y = acc[i][1] + bias.y;
        o.z = acc[i][2] + bias.z;
        o.w = acc[i][3] + bias.w;
        *(float4*)(h + (size_t)(row + i) * H1 + col) = o;
    }
}

// ---------------- GEMM2: feats = gelu(h) @ W2 + b2 (R7 version, verified) ----------------
__global__ __launch_bounds__(256) void mlp2_kernel(const float* __restrict__ h,
                                                   const float* __restrict__ W2,
                                                   const float* __restrict__ b2,
                                                   float* __restrict__ feats) {
    __shared__ float hs[32 * HSTR];    // 32.9 KB
    __shared__ float w2s[H1 * DOUT];   // 32 KB
    const int blk = blockIdx.x;
    const int tid = threadIdx.x;

    for (int i = tid; i < (H1 * DOUT) / 4; i += 256)
        ((float4*)w2s)[i] = ((const float4*)W2)[i];

    const float* hb = h + (size_t)blk * 32 * H1;
    const int sr = tid & 31;          // staging row 0..31
    const int sk = (tid >> 5) * 32;   // staging k-base (8 groups of 32)
    const float* hrow = hb + (size_t)sr * H1 + sk;
#pragma unroll
    for (int j = 0; j < 8; ++j) {
        float4 v = ((const float4*)hrow)[j];
        hs[sr * HSTR + sk + 4 * j + 0] = gelu_exact(v.x);
        hs[sr * HSTR + sk + 4 * j + 1] = gelu_exact(v.y);
        hs[sr * HSTR + sk + 4 * j + 2] = gelu_exact(v.z);
        hs[sr * HSTR + sk + 4 * j + 3] = gelu_exact(v.w);
    }
    __syncthreads();

    const int row = tid >> 3;         // 0..31
    const int col4 = (tid & 7) * 4;   // 0,4,..,28
    const float4 bias = ((const float4*)b2)[tid & 7];
    float a0 = 0.f, a1 = 0.f, a2 = 0.f, a3 = 0.f;
    const float* hr = &hs[row * HSTR];
    for (int k = 0; k < H1; ++k) {
        float a = hr[k];
        float4 w = *(const float4*)&w2s[k * DOUT + col4];
        a0 = fmaf(a, w.x, a0);
        a1 = fmaf(a, w.y, a1);
        a2 = fmaf(a, w.z, a2);
        a3 = fmaf(a, w.w, a3);
    }
    float4 o;
    o.x = a0 + bias.x;
    o.y = a1 + bias.y;
    o.z = a2 + bias.z;
    o.w = a3 + bias.w;
    *(float4*)(feats + (size_t)(blk * 32 + row) * DOUT + col4) = o;
}

// ---------------- Ward clustering: Lance-Williams recurrence (NO Gram matrix) ----------------
// D(m,k) = ((si+sk)*D(i,k) + (sj+sk)*D(j,k) - sk*D(i,j)) / (si+sj+sk)  -- operates on the
// stored Ward merge costs directly; D(i,j) = argmin value (in registers). Removes per
// iteration: G row+column writes, Gii/Gij/Gjj readlane chain, qn/dot machinery, and the
// whole Gram half of init + 67.6 KB LDS. Equal to the Gram path in exact arithmetic;
// Dn >= Dij >= 0 exactly (Cik,Cjk >= global min), clamp guards rounding at ~0.
__global__ __launch_bounds__(256) void ward_kernel(const float* __restrict__ feats,
                                                   int* __restrict__ out) {
    __shared__ __align__(16) float cost[NPTS * RSTR];  // 67.6 KB
    __shared__ float centsT[32 * CSTR];                // init staging only
    __shared__ unsigned long long rowkey[NPTS];
    __shared__ float sqArr[NPTS];
    __shared__ float szsE[NPTS];
    __shared__ int rnk[NPTS];

    const int b = blockIdx.x;
    const int tid = threadIdx.x;
    const float* f = feats + (size_t)b * NPTS * DOUT;
    const float INF = __builtin_inff();

    // ---- init (all 4 waves) ----
    for (int i = tid; i < NPTS * DOUT; i += 256) {
        int r = i >> 5, d = i & 31;
        centsT[d * CSTR + r] = f[i];
    }
    __syncthreads();
    if (tid < NPTS) {
        float s = 0.f;
#pragma unroll
        for (int d = 0; d < 32; ++d) {
            float v = centsT[d * CSTR + tid];
            s = fmaf(v, v, s);
        }
        sqArr[tid] = s;
    }
    __syncthreads();
    {
        int ti = tid >> 4, tj = tid & 15;
        int I0 = ti * 8, J0 = tj * 8;
        float acc[8][8];
#pragma unroll
        for (int u = 0; u < 8; ++u)
#pragma unroll
            for (int v = 0; v < 8; ++v) acc[u][v] = 0.f;
        for (int d = 0; d < 32; ++d) {
            float a[8], bb[8];
#pragma unroll
            for (int u = 0; u < 8; ++u) a[u] = centsT[d * CSTR + I0 + u];
#pragma unroll
            for (int v = 0; v < 8; ++v) bb[v] = centsT[d * CSTR + J0 + v];
#pragma unroll
            for (int u = 0; u < 8; ++u)
#pragma unroll
                for (int v = 0; v < 8; ++v)
                    acc[u][v] = fmaf(a[u], bb[v], acc[u][v]);
        }
#pragma unroll
        for (int u = 0; u < 8; ++u) {
#pragma unroll
            for (int v = 0; v < 8; ++v) {
                int i = I0 + u, j = J0 + v;
                float d2 = sqArr[i] + sqArr[j] - 2.0f * acc[u][v];
                if (d2 < 0.f) d2 = 0.f;
                float w = (1.0f * 1.0f) / (1.0f + 1.0f + 1e-30f);
                cost[i * RSTR + j] = (i == j) ? INF : w * d2;
            }
        }
    }
    __syncthreads();
    if (tid < NPTS) {
        unsigned long long best = DEADKEY;
        for (int j = 0; j < NPTS; ++j) {
            float v = cost[tid * RSTR + j];
            unsigned long long k = mkkey(v, tid, j);
            if (k < best) best = k;
        }
        rowkey[tid] = best;
    }
    __syncthreads();

    if (tid >= 64) return;  // wave 0 only
    const int lane = tid;
    const int hh = lane & 31;
    const int r0 = lane * 2, r1 = lane * 2 + 1;

    unsigned long long k0 = rowkey[r0], k1 = rowkey[r1];
    float s0 = 1.0f, s1 = 1.0f;
    int lab0 = r0, lab1 = r1;
    unsigned long long alive0 = ~0ull, alive1 = ~0ull;

    for (int it = 0; it < NPTS - KCL; ++it) {
        // P1: global argmin via u32-bits DPP min + ballot (exact flat-index tie-break)
        unsigned bv0 = (unsigned)(k0 >> 32), bv1 = (unsigned)(k1 >> 32);
        unsigned lmin = bv0 < bv1 ? bv0 : bv1;
        unsigned lflat = (bv0 <= bv1) ? (unsigned)(k0 & 0x3FFFu) : (unsigned)(k1 & 0x3FFFu);
        unsigned gmin = wave_umin_bcast(lmin);
        unsigned long long bmask = __ballot(lmin == gmin);
        int lsel = __ffsll(bmask) - 1;
        unsigned flat = (unsigned)__builtin_amdgcn_readlane((int)lflat, lsel);
        int ra = (int)(flat >> 7), ca = (int)(flat & 127u);
        const int i2 = ra < ca ? ra : ca;
        const int j2 = ra < ca ? ca : ra;
        const float Dij = __uint_as_float(gmin);

        // cost rows i2, j2 (issued early; only depend on i2/j2)
        float2 ci = *(const float2*)&cost[i2 * RSTR + r0];
        float2 cj = *(const float2*)&cost[j2 * RSTR + r0];

        float si = readlanef((i2 & 1) ? s1 : s0, i2 >> 1);
        float sj = readlanef((j2 & 1) ? s1 : s0, j2 >> 1);
        const float snew = si + sj;

        int arg0 = (int)(k0 & 127u), arg1 = (int)(k1 & 127u);
        bool d0 = (s0 > 0.f) && r0 != i2 && r0 != j2 && (arg0 == i2 || arg0 == j2);
        bool d1 = (s1 > 0.f) && r1 != i2 && r1 != j2 && (arg1 == i2 || arg1 == j2);
        unsigned long long m0 = __ballot(d0), m1 = __ballot(d1);

        // Lance-Williams update (pre-update sizes; valid rows' sizes are unchanged)
        float Dn0 = ((si + s0) * ci.x + (sj + s0) * cj.x - s0 * Dij) / (snew + s0);
        float Dn1 = ((si + s1) * ci.y + (sj + s1) * cj.y - s1 * Dij) / (snew + s1);
        if (Dn0 < 0.f) Dn0 = 0.f;
        if (Dn1 < 0.f) Dn1 = 0.f;

        // state updates
        if (lab0 == j2) lab0 = i2;
        if (lab1 == j2) lab1 = i2;
        if (r0 == i2) s0 = snew; else if (r0 == j2) { s0 = 0.f; k0 = DEADKEY; }
        if (r1 == i2) s1 = snew; else if (r1 == j2) { s1 = 0.f; k1 = DEADKEY; }
        if (j2 < 64) alive0 &= ~(1ull << j2); else alive1 &= ~(1ull << (j2 - 64));

        // cost writes for row/col i2 + key updates
        bool w0 = (s0 > 0.f) && r0 != i2 && r0 != j2;
        bool w1 = (s1 > 0.f) && r1 != i2 && r1 != j2;
        if (w0) {
            cost[r0 * RSTR + i2] = Dn0;
            cost[i2 * RSTR + r0] = Dn0;
            if (!d0) {
                unsigned long long nk = mkkey(Dn0, r0, i2);
                if (nk < k0) k0 = nk;
            }
        }
        if (w1) {
            cost[r1 * RSTR + i2] = Dn1;
            cost[i2 * RSTR + r1] = Dn1;
            if (!d1) {
                unsigned long long nk = mkkey(Dn1, r1, i2);
                if (nk < k1) k1 = nk;
            }
        }

        // rescans: row i2 (always) + dirty rows; 2 rows/round, b128 + alive-mask + u32 half-min
        bool pi = true;
        unsigned long long mm0 = m0, mm1 = m1;
        while (pi | (mm0 != 0ull) | (mm1 != 0ull)) {
            int rA, rB;
            bool hasB = false;
            if (pi) { rA = i2; pi = false; }
            else if (mm0) { int t = __ffsll(mm0) - 1; rA = 2 * t; mm0 &= mm0 - 1; }
            else { int t = __ffsll(mm1) - 1; rA = 2 * t + 1; mm1 &= mm1 - 1; }
            if (mm0) { int t = __ffsll(mm0) - 1; rB = 2 * t; mm0 &= mm0 - 1; hasB = true; }
            else if (mm1) { int t = __ffsll(mm1) - 1; rB = 2 * t + 1; mm1 &= mm1 - 1; hasB = true; }
            else rB = rA;

            int r = (lane < 32) ? rA : rB;
            float4 cv = *(const float4*)&cost[r * RSTR + 4 * hh];
            unsigned long long word = (hh < 16) ? alive0 : alive1;
            unsigned nib = (unsigned)(word >> ((4 * hh) & 63)) & 0xFu;
            unsigned e0 = (nib & 1u) ? __float_as_uint(cv.x) : 0xFFFFFFFFu;
            unsigned e1 = (nib & 2u) ? __float_as_uint(cv.y) : 0xFFFFFFFFu;
            unsigned e2 = (nib & 4u) ? __float_as_uint(cv.z) : 0xFFFFFFFFu;
            unsigned e3 = (nib & 8u) ? __float_as_uint(cv.w) : 0xFFFFFFFFu;
            unsigned m = e0; int c = 0;
            if (e1 < m) { m = e1; c = 1; }
            if (e2 < m) { m = e2; c = 2; }
            if (e3 < m) { m = e3; c = 3; }
            int lcol = 4 * hh + c;
            unsigned hm = half_umin(m);
            unsigned vA = (unsigned)__builtin_amdgcn_readlane((int)hm, 31);
            unsigned vB = (unsigned)__builtin_amdgcn_readlane((int)hm, 63);
            unsigned vref = (lane < 32) ? vA : vB;
            unsigned long long msk = __ballot(m == vref);
            int laneA = __ffsll(msk & 0xFFFFFFFFull) - 1;
            int laneB = 32 + __ffsll(msk >> 32) - 1;
            int colA = __builtin_amdgcn_readlane(lcol, laneA);
            int colB = __builtin_amdgcn_readlane(lcol, laneB);
            unsigned long long keyA = ((unsigned long long)vA << 32) | (unsigned)((rA << 7) | colA);
            unsigned long long keyB = ((unsigned long long)vB << 32) | (unsigned)((rB << 7) | colB);
            if (lane == (rA >> 1)) { if (rA & 1) k1 = keyA; else k0 = keyA; }
            if (hasB && lane == (rB >> 1)) { if (rB & 1) k1 = keyB; else k0 = keyB; }
        }
    }

    // final relabel
    szsE[r0] = s0;
    szsE[r1] = s1;
    __asm__ volatile("s_waitcnt lgkmcnt(0)" ::: "memory");
    if (lane == 0) {
        int c = 0;
        for (int i = 0; i < NPTS; ++i) rnk[i] = (szsE[i] > 0.f) ? c++ : -1;
    }
    __asm__ volatile("s_waitcnt lgkmcnt(0)" ::: "memory");
    out[b * NPTS + r0] = rnk[lab0];
    out[b * NPTS + r1] = rnk[lab1];
}

extern "C" void kernel_launch(void* const* d_in, const int* in_sizes, int n_in,
                              void* d_out, int out_size, void* d_ws, size_t ws_size,
                              hipStream_t stream) {
    const float* x  = (const float*)d_in[0];
    const float* W1 = (const float*)d_in[1];
    const float* b1 = (const float*)d_in[2];
    const float* W2 = (const float*)d_in[3];
    const float* b2 = (const float*)d_in[4];

    float* h = (float*)d_ws;                          // 16 MB
    float* feats = h + (size_t)MROWS * H1;            // 2 MB
    float* gx = feats + (size_t)MROWS * DOUT;         // 64 MB (if it fits)
    int* out = (int*)d_out;

    const size_t need = ((size_t)MROWS * H1 + (size_t)MROWS * DOUT + (size_t)MROWS * DIN) * 4;
    const bool use_gx = ws_size >= need;

    if (use_gx) {
        gelu_kernel<<<2048, 256, 0, stream>>>(x, gx, MROWS * DIN / 4);
        mlp1_kernel<false><<<dim3(H1 / 64, MROWS / 64), 256, 0, stream>>>(gx, W1, b1, h);
    } else {
        mlp1_kernel<true><<<dim3(H1 / 64, MROWS / 64), 256, 0, stream>>>(x, W1, b1, h);
    }
    mlp2_kernel<<<MROWS / 32, 256, 0, stream>>>(h, W2, b2, feats);
    ward_kernel<<<BB, 256, 0, stream>>>(feats, out);
}

// Round 12
// 387.162 us; speedup vs baseline: 1.1521x; 1.1154x over previous
//
#include <hip/hip_runtime.h>
#include <math.h>

#define BB 128
#define NN 128
#define DIN 1024
#define H1 256
#define DOUT 32
#define KCL 8
#define NPTS 128
#define MROWS (BB*NN)   // 16384
#define CSTR 130        // centsT row stride (words, init staging only)
#define RSTR 132        // cost row stride (words, 16B aligned)
#define HSTR 257        // mlp2 h-chunk row stride (odd -> conflict-free reads)
#define DEADKEY 0xFFFFFFFF00000000ull

typedef _Float16 f16;
typedef f16 f16x8 __attribute__((ext_vector_type(8)));
typedef float f32x4 __attribute__((ext_vector_type(4)));

__device__ __forceinline__ float gelu_exact(float v) {
    return 0.5f * v * (1.0f + erff(v * 0.70710678118654752f));
}

__device__ __forceinline__ unsigned long long mkkey(float v, int r, int j) {
    return ((unsigned long long)__float_as_uint(v) << 32) | (unsigned)((r << 7) | j);
}

__device__ __forceinline__ float readlanef(float v, int lane) {
    return __int_as_float(__builtin_amdgcn_readlane(__float_as_int(v), lane));
}

// u32 min via DPP (costs are >=0 floats: IEEE order == unsigned bit order)
template<int CTRL, int RMASK>
__device__ __forceinline__ unsigned dpp_umin_step(unsigned v) {
    unsigned t = (unsigned)__builtin_amdgcn_update_dpp((int)v, (int)v, CTRL, RMASK, 0xf, false);
    return t < v ? t : v;
}
__device__ __forceinline__ unsigned wave_umin_bcast(unsigned v) {
    v = dpp_umin_step<0x111, 0xf>(v);
    v = dpp_umin_step<0x112, 0xf>(v);
    v = dpp_umin_step<0x114, 0xf>(v);
    v = dpp_umin_step<0x118, 0xf>(v);
    v = dpp_umin_step<0x142, 0xa>(v);
    v = dpp_umin_step<0x143, 0xc>(v);
    return (unsigned)__builtin_amdgcn_readlane((int)v, 63);
}
// lane31 = min(lanes0..31), lane63 = min(lanes32..63)
__device__ __forceinline__ unsigned half_umin(unsigned v) {
    v = dpp_umin_step<0x111, 0xf>(v);
    v = dpp_umin_step<0x112, 0xf>(v);
    v = dpp_umin_step<0x114, 0xf>(v);
    v = dpp_umin_step<0x118, 0xf>(v);
    v = dpp_umin_step<0x142, 0xa>(v);
    return v;
}

// 3-way f16 split: g = h + l + q with residual ~|g|*2^-33 (or < f16 subnormal floor)
__device__ __forceinline__ void split3(float g, unsigned short &uh, unsigned short &ul,
                                       unsigned short &uq) {
    f16 h = (f16)g;
    float r = g - (float)h;
    f16 l = (f16)r;
    float r2 = r - (float)l;
    f16 q = (f16)r2;
    uh = __builtin_bit_cast(unsigned short, h);
    ul = __builtin_bit_cast(unsigned short, l);
    uq = __builtin_bit_cast(unsigned short, q);
}

// ---------------- prep: gxh/l/q = split3(gelu(x)), memory-bound ----------------
__global__ __launch_bounds__(256) void prep_kernel(const float* __restrict__ x,
                                                   unsigned short* __restrict__ gh,
                                                   unsigned short* __restrict__ gl,
                                                   unsigned short* __restrict__ gq, int n4) {
    int i = blockIdx.x * 256 + threadIdx.x;
    const int stride = gridDim.x * 256;
    for (; i < n4; i += stride) {
        float4 v = ((const float4*)x)[i];
        ushort4 oh, ol, oq;
        split3(gelu_exact(v.x), oh.x, ol.x, oq.x);
        split3(gelu_exact(v.y), oh.y, ol.y, oq.y);
        split3(gelu_exact(v.z), oh.z, ol.z, oq.z);
        split3(gelu_exact(v.w), oh.w, ol.w, oq.w);
        ((ushort4*)gh)[i] = oh;
        ((ushort4*)gl)[i] = ol;
        ((ushort4*)gq)[i] = oq;
    }
}

// ---------------- w1prep: W1 [K][N] fp32 -> W1T h/l/q [N][K] f16 (one-time, 1MB) ----------------
__global__ __launch_bounds__(256) void w1prep_kernel(const float* __restrict__ W1,
                                                     unsigned short* __restrict__ th,
                                                     unsigned short* __restrict__ tl,
                                                     unsigned short* __restrict__ tq) {
    const int n = blockIdx.x * 4 + (threadIdx.x >> 6);  // 64 blocks x 4 = 256
    const int t = threadIdx.x & 63;                     // k-group: k = t*16 + i
    unsigned short ah[16], al[16], aq[16];
#pragma unroll
    for (int i = 0; i < 16; ++i) {
        int k = t * 16 + i;
        split3(W1[(size_t)k * H1 + n], ah[i], al[i], aq[i]);
    }
    const size_t base = (size_t)n * DIN + t * 16;
#pragma unroll
    for (int j = 0; j < 4; ++j) {
        *(ushort4*)(th + base + 4 * j) = make_ushort4(ah[4*j], ah[4*j+1], ah[4*j+2], ah[4*j+3]);
        *(ushort4*)(tl + base + 4 * j) = make_ushort4(al[4*j], al[4*j+1], al[4*j+2], al[4*j+3]);
        *(ushort4*)(tq + base + 4 * j) = make_ushort4(aq[4*j], aq[4*j+1], aq[4*j+2], aq[4*j+3]);
    }
}

// ---------------- GEMM1 (MFMA): h = (gh+gl+gq)@(wh+wl+wq)^T + b1, 6-product f16 split ----------------
// 64x64 tile, K-step 32, 4 waves: wave w owns rows w*16..w*16+15, 4 col-tiles of 16.
// All 6 operand tiles ([64][32] f16, linear) staged via global_load_lds; wave w stages
// sub-chunk g=w (rows w*16..+15) of every tile -> fully static addressing.
// Fragments: b128 per lane from row-major [16][32] f16: row=l&15, k=(l>>4)*8 (A and B^T).
// C/D: col=lane&15, row=(lane>>4)*4+reg (HW-verified mapping).
// Error vs fp32 reference ~1e-8 relative (< the LW/XLA rounding differences that pass).
__global__ __launch_bounds__(256) void mlp1_mfma(const f16* __restrict__ gxh,
                                                 const f16* __restrict__ gxl,
                                                 const f16* __restrict__ gxq,
                                                 const f16* __restrict__ wth,
                                                 const f16* __restrict__ wtl,
                                                 const f16* __restrict__ wtq,
                                                 const float* __restrict__ b1,
                                                 float* __restrict__ h) {
    __shared__ __align__(16) f16 T[6][64 * 32];  // 6 x 4KB = 24KB
    const int bn = blockIdx.x;   // 4 col-tiles of 64
    const int bm = blockIdx.y;   // 256 row-tiles of 64
    const int tid = threadIdx.x;
    const int w = tid >> 6, l = tid & 63;

    const f16* pA0 = gxh + (size_t)(bm * 64) * DIN;
    const f16* pA1 = gxl + (size_t)(bm * 64) * DIN;
    const f16* pA2 = gxq + (size_t)(bm * 64) * DIN;
    const f16* pB0 = wth + (size_t)(bn * 64) * DIN;
    const f16* pB1 = wtl + (size_t)(bn * 64) * DIN;
    const f16* pB2 = wtq + (size_t)(bn * 64) * DIN;

    f32x4 acc[4];
#pragma unroll
    for (int ct = 0; ct < 4; ++ct) acc[ct] = (f32x4){0.f, 0.f, 0.f, 0.f};

    const int grow = l >> 2;        // 0..15 row within this wave's 16-row chunk
    const int gcol = (l & 3) * 8;   // halfword offset 0,8,16,24
    const int fr = l & 15, fk = (l >> 4) * 8;

    for (int kt = 0; kt < DIN; kt += 32) {
        __syncthreads();
#define STAGE(T6, SRC)                                                               \
        {                                                                            \
            const f16* s = SRC + (size_t)(w * 16 + grow) * DIN + kt + gcol;          \
            __builtin_amdgcn_global_load_lds(                                        \
                (const __attribute__((address_space(1))) unsigned int*)s,            \
                (__attribute__((address_space(3))) unsigned int*)&T[T6][w * 512],    \
                16, 0, 0);                                                           \
        }
        STAGE(0, pA0) STAGE(1, pA1) STAGE(2, pA2)
        STAGE(3, pB0) STAGE(4, pB1) STAGE(5, pB2)
#undef STAGE
        __syncthreads();  // vmcnt(0) drain: all 6 tiles resident

        f16x8 Ah = *(const f16x8*)&T[0][(w * 16 + fr) * 32 + fk];
        f16x8 Al = *(const f16x8*)&T[1][(w * 16 + fr) * 32 + fk];
        f16x8 Aq = *(const f16x8*)&T[2][(w * 16 + fr) * 32 + fk];
#pragma unroll
        for (int ct = 0; ct < 4; ++ct) {
            f16x8 Bh = *(const f16x8*)&T[3][(ct * 16 + fr) * 32 + fk];
            f16x8 Bl = *(const f16x8*)&T[4][(ct * 16 + fr) * 32 + fk];
            f16x8 Bq = *(const f16x8*)&T[5][(ct * 16 + fr) * 32 + fk];
            f32x4 a = acc[ct];
            a = __builtin_amdgcn_mfma_f32_16x16x32_f16(Ah, Bh, a, 0, 0, 0);
            a = __builtin_amdgcn_mfma_f32_16x16x32_f16(Ah, Bl, a, 0, 0, 0);
            a = __builtin_amdgcn_mfma_f32_16x16x32_f16(Al, Bh, a, 0, 0, 0);
            a = __builtin_amdgcn_mfma_f32_16x16x32_f16(Ah, Bq, a, 0, 0, 0);
            a = __builtin_amdgcn_mfma_f32_16x16x32_f16(Aq, Bh, a, 0, 0, 0);
            a = __builtin_amdgcn_mfma_f32_16x16x32_f16(Al, Bl, a, 0, 0, 0);
            acc[ct] = a;
        }
    }

    const int orow = bm * 64 + w * 16 + (l >> 4) * 4;
    const int ocol0 = bn * 64 + (l & 15);
#pragma unroll
    for (int ct = 0; ct < 4; ++ct) {
        const int col = ocol0 + ct * 16;
        const float bias = b1[col];
#pragma unroll
        for (int r = 0; r < 4; ++r)
            h[(size_t)(orow + r) * H1 + col] = acc[ct][r] + bias;
    }
}

// ---------------- GEMM1 fallback (fp32, FUSE gelu, glds-B) for small workspace ----------------
__global__ __launch_bounds__(256) void mlp1_kernel(const float* __restrict__ xin,
                                                   const float* __restrict__ W1,
                                                   const float* __restrict__ b1,
                                                   float* __restrict__ h) {
    __shared__ float As[64][68];
    __shared__ float Bs[64][64];
    const int bn = blockIdx.x;
    const int bm = blockIdx.y;
    const int tid = threadIdx.x;
    const int tx = tid & 15, ty = tid >> 4;

    float acc[4][4] = {{0.f}};
    const int arow = tid >> 2;
    const int kc = (tid & 3) * 4;
    const int wv = tid >> 6;
    const int ln = tid & 63;
    const int bkr = ln >> 4;
    const int bkc = (ln & 15) * 4;

    const float* xrow = xin + (size_t)(bm * 64 + arow) * DIN;
    const float* wbase = W1 + bn * 64;

    for (int kt = 0; kt < DIN; kt += 64) {
        float4 a0 = *(const float4*)(xrow + kt + kc);
        float4 a1 = *(const float4*)(xrow + kt + kc + 16);
        float4 a2 = *(const float4*)(xrow + kt + kc + 32);
        float4 a3 = *(const float4*)(xrow + kt + kc + 48);
        __syncthreads();
#pragma unroll
        for (int s = 0; s < 4; ++s) {
            const int kr = wv * 16 + s * 4;
            const float* g = wbase + (size_t)(kt + kr + bkr) * H1 + bkc;
            __builtin_amdgcn_global_load_lds(
                (const __attribute__((address_space(1))) unsigned int*)g,
                (__attribute__((address_space(3))) unsigned int*)&Bs[kr][0], 16, 0, 0);
        }
        As[kc + 0][arow] = gelu_exact(a0.x);
        As[kc + 1][arow] = gelu_exact(a0.y);
        As[kc + 2][arow] = gelu_exact(a0.z);
        As[kc + 3][arow] = gelu_exact(a0.w);
        As[16 + kc + 0][arow] = gelu_exact(a1.x);
        As[16 + kc + 1][arow] = gelu_exact(a1.y);
        As[16 + kc + 2][arow] = gelu_exact(a1.z);
        As[16 + kc + 3][arow] = gelu_exact(a1.w);
        As[32 + kc + 0][arow] = gelu_exact(a2.x);
        As[32 + kc + 1][arow] = gelu_exact(a2.y);
        As[32 + kc + 2][arow] = gelu_exact(a2.z);
        As[32 + kc + 3][arow] = gelu_exact(a2.w);
        As[48 + kc + 0][arow] = gelu_exact(a3.x);
        As[48 + kc + 1][arow] = gelu_exact(a3.y);
        As[48 + kc + 2][arow] = gelu_exact(a3.z);
        As[48 + kc + 3][arow] = gelu_exact(a3.w);
        __syncthreads();
#pragma unroll
        for (int kk = 0; kk < 64; ++kk) {
            float4 a = *(const float4*)&As[kk][ty * 4];
            float4 b = *(const float4*)&Bs[kk][tx * 4];
            float ar[4] = {a.x, a.y, a.z, a.w};
            float br[4] = {b.x, b.y, b.z, b.w};
#pragma unroll
            for (int i = 0; i < 4; ++i)
#pragma unroll
                for (int j = 0; j < 4; ++j)
                    acc[i][j] = fmaf(ar[i], br[j], acc[i][j]);
        }
    }

    const int row = bm * 64 + ty * 4;
    const int col = bn * 64 + tx * 4;
    float4 bias = *(const float4*)(b1 + col);
#pragma unroll
    for (int i = 0; i < 4; ++i) {
        float4 o;
        o.x = acc[i][0] + bias.x;
        o.y = acc[i][1] + bias.y;
        o.z = acc[i][2] + bias.z;
        o.w = acc[i][3] + bias.w;
        *(float4*)(h + (size_t)(row + i) * H1 + col) = o;
    }
}

// ---------------- GEMM2: feats = gelu(h) @ W2 + b2 (R7 version, verified) ----------------
__global__ __launch_bounds__(256) void mlp2_kernel(const float* __restrict__ h,
                                                   const float* __restrict__ W2,
                                                   const float* __restrict__ b2,
                                                   float* __restrict__ feats) {
    __shared__ float hs[32 * HSTR];
    __shared__ float w2s[H1 * DOUT];
    const int blk = blockIdx.x;
    const int tid = threadIdx.x;

    for (int i = tid; i < (H1 * DOUT) / 4; i += 256)
        ((float4*)w2s)[i] = ((const float4*)W2)[i];

    const float* hb = h + (size_t)blk * 32 * H1;
    const int sr = tid & 31;
    const int sk = (tid >> 5) * 32;
    const float* hrow = hb + (size_t)sr * H1 + sk;
#pragma unroll
    for (int j = 0; j < 8; ++j) {
        float4 v = ((const float4*)hrow)[j];
        hs[sr * HSTR + sk + 4 * j + 0] = gelu_exact(v.x);
        hs[sr * HSTR + sk + 4 * j + 1] = gelu_exact(v.y);
        hs[sr * HSTR + sk + 4 * j + 2] = gelu_exact(v.z);
        hs[sr * HSTR + sk + 4 * j + 3] = gelu_exact(v.w);
    }
    __syncthreads();

    const int row = tid >> 3;
    const int col4 = (tid & 7) * 4;
    const float4 bias = ((const float4*)b2)[tid & 7];
    float a0 = 0.f, a1 = 0.f, a2 = 0.f, a3 = 0.f;
    const float* hr = &hs[row * HSTR];
    for (int k = 0; k < H1; ++k) {
        float a = hr[k];
        float4 w = *(const float4*)&w2s[k * DOUT + col4];
        a0 = fmaf(a, w.x, a0);
        a1 = fmaf(a, w.y, a1);
        a2 = fmaf(a, w.z, a2);
        a3 = fmaf(a, w.w, a3);
    }
    float4 o;
    o.x = a0 + bias.x;
    o.y = a1 + bias.y;
    o.z = a2 + bias.z;
    o.w = a3 + bias.w;
    *(float4*)(feats + (size_t)(blk * 32 + row) * DOUT + col4) = o;
}

// ---------------- Ward clustering: Lance-Williams recurrence (R10, verified) ----------------
__global__ __launch_bounds__(256) void ward_kernel(const float* __restrict__ feats,
                                                   int* __restrict__ out) {
    __shared__ __align__(16) float cost[NPTS * RSTR];  // 67.6 KB
    __shared__ float centsT[32 * CSTR];                // init staging only
    __shared__ unsigned long long rowkey[NPTS];
    __shared__ float sqArr[NPTS];
    __shared__ float szsE[NPTS];
    __shared__ int rnk[NPTS];

    const int b = blockIdx.x;
    const int tid = threadIdx.x;
    const float* f = feats + (size_t)b * NPTS * DOUT;
    const float INF = __builtin_inff();

    // ---- init (all 4 waves) ----
    for (int i = tid; i < NPTS * DOUT; i += 256) {
        int r = i >> 5, d = i & 31;
        centsT[d * CSTR + r] = f[i];
    }
    __syncthreads();
    if (tid < NPTS) {
        float s = 0.f;
#pragma unroll
        for (int d = 0; d < 32; ++d) {
            float v = centsT[d * CSTR + tid];
            s = fmaf(v, v, s);
        }
        sqArr[tid] = s;
    }
    __syncthreads();
    {
        int ti = tid >> 4, tj = tid & 15;
        int I0 = ti * 8, J0 = tj * 8;
        float acc[8][8];
#pragma unroll
        for (int u = 0; u < 8; ++u)
#pragma unroll
            for (int v = 0; v < 8; ++v) acc[u][v] = 0.f;
        for (int d = 0; d < 32; ++d) {
            float a[8], bb[8];
#pragma unroll
            for (int u = 0; u < 8; ++u) a[u] = centsT[d * CSTR + I0 + u];
#pragma unroll
            for (int v = 0; v < 8; ++v) bb[v] = centsT[d * CSTR + J0 + v];
#pragma unroll
            for (int u = 0; u < 8; ++u)
#pragma unroll
                for (int v = 0; v < 8; ++v)
                    acc[u][v] = fmaf(a[u], bb[v], acc[u][v]);
        }
#pragma unroll
        for (int u = 0; u < 8; ++u) {
#pragma unroll
            for (int v = 0; v < 8; ++v) {
                int i = I0 + u, j = J0 + v;
                float d2 = sqArr[i] + sqArr[j] - 2.0f * acc[u][v];
                if (d2 < 0.f) d2 = 0.f;
                float w = (1.0f * 1.0f) / (1.0f + 1.0f + 1e-30f);
                cost[i * RSTR + j] = (i == j) ? INF : w * d2;
            }
        }
    }
    __syncthreads();
    if (tid < NPTS) {
        unsigned long long best = DEADKEY;
        for (int j = 0; j < NPTS; ++j) {
            float v = cost[tid * RSTR + j];
            unsigned long long k = mkkey(v, tid, j);
            if (k < best) best = k;
        }
        rowkey[tid] = best;
    }
    __syncthreads();

    if (tid >= 64) return;  // wave 0 only
    const int lane = tid;
    const int hh = lane & 31;
    const int r0 = lane * 2, r1 = lane * 2 + 1;

    unsigned long long k0 = rowkey[r0], k1 = rowkey[r1];
    float s0 = 1.0f, s1 = 1.0f;
    int lab0 = r0, lab1 = r1;
    unsigned long long alive0 = ~0ull, alive1 = ~0ull;

    for (int it = 0; it < NPTS - KCL; ++it) {
        unsigned bv0 = (unsigned)(k0 >> 32), bv1 = (unsigned)(k1 >> 32);
        unsigned lmin = bv0 < bv1 ? bv0 : bv1;
        unsigned lflat = (bv0 <= bv1) ? (unsigned)(k0 & 0x3FFFu) : (unsigned)(k1 & 0x3FFFu);
        unsigned gmin = wave_umin_bcast(lmin);
        unsigned long long bmask = __ballot(lmin == gmin);
        int lsel = __ffsll(bmask) - 1;
        unsigned flat = (unsigned)__builtin_amdgcn_readlane((int)lflat, lsel);
        int ra = (int)(flat >> 7), ca = (int)(flat & 127u);
        const int i2 = ra < ca ? ra : ca;
        const int j2 = ra < ca ? ca : ra;
        const float Dij = __uint_as_float(gmin);

        float2 ci = *(const float2*)&cost[i2 * RSTR + r0];
        float2 cj = *(const float2*)&cost[j2 * RSTR + r0];

        float si = readlanef((i2 & 1) ? s1 : s0, i2 >> 1);
        float sj = readlanef((j2 & 1) ? s1 : s0, j2 >> 1);
        const float snew = si + sj;

        int arg0 = (int)(k0 & 127u), arg1 = (int)(k1 & 127u);
        bool d0 = (s0 > 0.f) && r0 != i2 && r0 != j2 && (arg0 == i2 || arg0 == j2);
        bool d1 = (s1 > 0.f) && r1 != i2 && r1 != j2 && (arg1 == i2 || arg1 == j2);
        unsigned long long m0 = __ballot(d0), m1 = __ballot(d1);

        float Dn0 = ((si + s0) * ci.x + (sj + s0) * cj.x - s0 * Dij) / (snew + s0);
        float Dn1 = ((si + s1) * ci.y + (sj + s1) * cj.y - s1 * Dij) / (snew + s1);
        if (Dn0 < 0.f) Dn0 = 0.f;
        if (Dn1 < 0.f) Dn1 = 0.f;

        if (lab0 == j2) lab0 = i2;
        if (lab1 == j2) lab1 = i2;
        if (r0 == i2) s0 = snew; else if (r0 == j2) { s0 = 0.f; k0 = DEADKEY; }
        if (r1 == i2) s1 = snew; else if (r1 == j2) { s1 = 0.f; k1 = DEADKEY; }
        if (j2 < 64) alive0 &= ~(1ull << j2); else alive1 &= ~(1ull << (j2 - 64));

        bool w0 = (s0 > 0.f) && r0 != i2 && r0 != j2;
        bool w1 = (s1 > 0.f) && r1 != i2 && r1 != j2;
        if (w0) {
            cost[r0 * RSTR + i2] = Dn0;
            cost[i2 * RSTR + r0] = Dn0;
            if (!d0) {
                unsigned long long nk = mkkey(Dn0, r0, i2);
                if (nk < k0) k0 = nk;
            }
        }
        if (w1) {
            cost[r1 * RSTR + i2] = Dn1;
            cost[i2 * RSTR + r1] = Dn1;
            if (!d1) {
                unsigned long long nk = mkkey(Dn1, r1, i2);
                if (nk < k1) k1 = nk;
            }
        }

        bool pi = true;
        unsigned long long mm0 = m0, mm1 = m1;
        while (pi | (mm0 != 0ull) | (mm1 != 0ull)) {
            int rA, rB;
            bool hasB = false;
            if (pi) { rA = i2; pi = false; }
            else if (mm0) { int t = __ffsll(mm0) - 1; rA = 2 * t; mm0 &= mm0 - 1; }
            else { int t = __ffsll(mm1) - 1; rA = 2 * t + 1; mm1 &= mm1 - 1; }
            if (mm0) { int t = __ffsll(mm0) - 1; rB = 2 * t; mm0 &= mm0 - 1; hasB = true; }
            else if (mm1) { int t = __ffsll(mm1) - 1; rB = 2 * t + 1; mm1 &= mm1 - 1; hasB = true; }
            else rB = rA;

            int r = (lane < 32) ? rA : rB;
            float4 cv = *(const float4*)&cost[r * RSTR + 4 * hh];
            unsigned long long word = (hh < 16) ? alive0 : alive1;
            unsigned nib = (unsigned)(word >> ((4 * hh) & 63)) & 0xFu;
            unsigned e0 = (nib & 1u) ? __float_as_uint(cv.x) : 0xFFFFFFFFu;
            unsigned e1 = (nib & 2u) ? __float_as_uint(cv.y) : 0xFFFFFFFFu;
            unsigned e2 = (nib & 4u) ? __float_as_uint(cv.z) : 0xFFFFFFFFu;
            unsigned e3 = (nib & 8u) ? __float_as_uint(cv.w) : 0xFFFFFFFFu;
            unsigned m = e0; int c = 0;
            if (e1 < m) { m = e1; c = 1; }
            if (e2 < m) { m = e2; c = 2; }
            if (e3 < m) { m = e3; c = 3; }
            int lcol = 4 * hh + c;
            unsigned hm = half_umin(m);
            unsigned vA = (unsigned)__builtin_amdgcn_readlane((int)hm, 31);
            unsigned vB = (unsigned)__builtin_amdgcn_readlane((int)hm, 63);
            unsigned vref = (lane < 32) ? vA : vB;
            unsigned long long msk = __ballot(m == vref);
            int laneA = __ffsll(msk & 0xFFFFFFFFull) - 1;
            int laneB = 32 + __ffsll(msk >> 32) - 1;
            int colA = __builtin_amdgcn_readlane(lcol, laneA);
            int colB = __builtin_amdgcn_readlane(lcol, laneB);
            unsigned long long keyA = ((unsigned long long)vA << 32) | (unsigned)((rA << 7) | colA);
            unsigned long long keyB = ((unsigned long long)vB << 32) | (unsigned)((rB << 7) | colB);
            if (lane == (rA >> 1)) { if (rA & 1) k1 = keyA; else k0 = keyA; }
            if (hasB && lane == (rB >> 1)) { if (rB & 1) k1 = keyB; else k0 = keyB; }
        }
    }

    szsE[r0] = s0;
    szsE[r1] = s1;
    __asm__ volatile("s_waitcnt lgkmcnt(0)" ::: "memory");
    if (lane == 0) {
        int c = 0;
        for (int i = 0; i < NPTS; ++i) rnk[i] = (szsE[i] > 0.f) ? c++ : -1;
    }
    __asm__ volatile("s_waitcnt lgkmcnt(0)" ::: "memory");
    out[b * NPTS + r0] = rnk[lab0];
    out[b * NPTS + r1] = rnk[lab1];
}

extern "C" void kernel_launch(void* const* d_in, const int* in_sizes, int n_in,
                              void* d_out, int out_size, void* d_ws, size_t ws_size,
                              hipStream_t stream) {
    const float* x  = (const float*)d_in[0];
    const float* W1 = (const float*)d_in[1];
    const float* b1 = (const float*)d_in[2];
    const float* W2 = (const float*)d_in[3];
    const float* b2 = (const float*)d_in[4];
    int* out = (int*)d_out;

    float* h = (float*)d_ws;                                   // 16.8 MB
    float* feats = h + (size_t)MROWS * H1;                     // 2.1 MB
    unsigned short* gxh = (unsigned short*)(feats + (size_t)MROWS * DOUT);
    unsigned short* gxl = gxh + (size_t)MROWS * DIN;           // 33.6 MB each
    unsigned short* gxq = gxl + (size_t)MROWS * DIN;
    unsigned short* wth = gxq + (size_t)MROWS * DIN;           // 0.52 MB each
    unsigned short* wtl = wth + (size_t)H1 * DIN;
    unsigned short* wtq = wtl + (size_t)H1 * DIN;

    const size_t need_mfma = ((size_t)MROWS * H1 + (size_t)MROWS * DOUT) * 4 +
                             (size_t)MROWS * DIN * 2 * 3 + (size_t)H1 * DIN * 2 * 3;

    if (ws_size >= need_mfma) {
        prep_kernel<<<2048, 256, 0, stream>>>(x, gxh, gxl, gxq, MROWS * DIN / 4);
        w1prep_kernel<<<64, 256, 0, stream>>>(W1, wth, wtl, wtq);
        mlp1_mfma<<<dim3(4, 256), 256, 0, stream>>>(
            (const f16*)gxh, (const f16*)gxl, (const f16*)gxq,
            (const f16*)wth, (const f16*)wtl, (const f16*)wtq, b1, h);
    } else {
        mlp1_kernel<<<dim3(4, 256), 256, 0, stream>>>(x, W1, b1, h);
    }
    mlp2_kernel<<<MROWS / 32, 256, 0, stream>>>(h, W2, b2, feats);
    ward_kernel<<<BB, 256, 0, stream>>>(feats, out);
}

// Round 13
// 384.062 us; speedup vs baseline: 1.1614x; 1.0081x over previous
//
#include <hip/hip_runtime.h>
#include <math.h>

#define BB 128
#define NN 128
#define DIN 1024
#define H1 256
#define DOUT 32
#define KCL 8
#define NPTS 128
#define MROWS (BB*NN)   // 16384
#define CSTR 130        // centsT row stride (words, init staging only)
#define RSTR 132        // cost row stride (words, 16B aligned)
#define HSTR 257        // mlp2 h-chunk row stride (odd -> conflict-free reads)
#define DEADKEY 0xFFFFFFFF00000000ull

typedef _Float16 f16;
typedef f16 f16x8 __attribute__((ext_vector_type(8)));
typedef float f32x4 __attribute__((ext_vector_type(4)));

__device__ __forceinline__ float gelu_exact(float v) {
    return 0.5f * v * (1.0f + erff(v * 0.70710678118654752f));
}

__device__ __forceinline__ unsigned long long mkkey(float v, int r, int j) {
    return ((unsigned long long)__float_as_uint(v) << 32) | (unsigned)((r << 7) | j);
}

__device__ __forceinline__ float readlanef(float v, int lane) {
    return __int_as_float(__builtin_amdgcn_readlane(__float_as_int(v), lane));
}

// u32 min via DPP (costs are >=0 floats: IEEE order == unsigned bit order)
template<int CTRL, int RMASK>
__device__ __forceinline__ unsigned dpp_umin_step(unsigned v) {
    unsigned t = (unsigned)__builtin_amdgcn_update_dpp((int)v, (int)v, CTRL, RMASK, 0xf, false);
    return t < v ? t : v;
}
__device__ __forceinline__ unsigned wave_umin_bcast(unsigned v) {
    v = dpp_umin_step<0x111, 0xf>(v);
    v = dpp_umin_step<0x112, 0xf>(v);
    v = dpp_umin_step<0x114, 0xf>(v);
    v = dpp_umin_step<0x118, 0xf>(v);
    v = dpp_umin_step<0x142, 0xa>(v);
    v = dpp_umin_step<0x143, 0xc>(v);
    return (unsigned)__builtin_amdgcn_readlane((int)v, 63);
}
// lane31 = min(lanes0..31), lane63 = min(lanes32..63)
__device__ __forceinline__ unsigned half_umin(unsigned v) {
    v = dpp_umin_step<0x111, 0xf>(v);
    v = dpp_umin_step<0x112, 0xf>(v);
    v = dpp_umin_step<0x114, 0xf>(v);
    v = dpp_umin_step<0x118, 0xf>(v);
    v = dpp_umin_step<0x142, 0xa>(v);
    return v;
}

// 3-way f16 split: g = h + l + q with residual ~|g|*2^-33 (or < f16 subnormal floor)
__device__ __forceinline__ void split3(float g, unsigned short &uh, unsigned short &ul,
                                       unsigned short &uq) {
    f16 h = (f16)g;
    float r = g - (float)h;
    f16 l = (f16)r;
    float r2 = r - (float)l;
    f16 q = (f16)r2;
    uh = __builtin_bit_cast(unsigned short, h);
    ul = __builtin_bit_cast(unsigned short, l);
    uq = __builtin_bit_cast(unsigned short, q);
}

// ---------------- prep: gxh/l/q = split3(gelu(x)), memory-bound ----------------
__global__ __launch_bounds__(256) void prep_kernel(const float* __restrict__ x,
                                                   unsigned short* __restrict__ gh,
                                                   unsigned short* __restrict__ gl,
                                                   unsigned short* __restrict__ gq, int n4) {
    int i = blockIdx.x * 256 + threadIdx.x;
    const int stride = gridDim.x * 256;
    for (; i < n4; i += stride) {
        float4 v = ((const float4*)x)[i];
        ushort4 oh, ol, oq;
        split3(gelu_exact(v.x), oh.x, ol.x, oq.x);
        split3(gelu_exact(v.y), oh.y, ol.y, oq.y);
        split3(gelu_exact(v.z), oh.z, ol.z, oq.z);
        split3(gelu_exact(v.w), oh.w, ol.w, oq.w);
        ((ushort4*)gh)[i] = oh;
        ((ushort4*)gl)[i] = ol;
        ((ushort4*)gq)[i] = oq;
    }
}

// ---------------- w1prep: W1 [K][N] fp32 -> W1T h/l/q [N][K] f16 (one-time, 1MB) ----------------
__global__ __launch_bounds__(256) void w1prep_kernel(const float* __restrict__ W1,
                                                     unsigned short* __restrict__ th,
                                                     unsigned short* __restrict__ tl,
                                                     unsigned short* __restrict__ tq) {
    const int n = blockIdx.x * 4 + (threadIdx.x >> 6);  // 64 blocks x 4 = 256
    const int t = threadIdx.x & 63;                     // k-group: k = t*16 + i
    unsigned short ah[16], al[16], aq[16];
#pragma unroll
    for (int i = 0; i < 16; ++i) {
        int k = t * 16 + i;
        split3(W1[(size_t)k * H1 + n], ah[i], al[i], aq[i]);
    }
    const size_t base = (size_t)n * DIN + t * 16;
#pragma unroll
    for (int j = 0; j < 4; ++j) {
        *(ushort4*)(th + base + 4 * j) = make_ushort4(ah[4*j], ah[4*j+1], ah[4*j+2], ah[4*j+3]);
        *(ushort4*)(tl + base + 4 * j) = make_ushort4(al[4*j], al[4*j+1], al[4*j+2], al[4*j+3]);
        *(ushort4*)(tq + base + 4 * j) = make_ushort4(aq[4*j], aq[4*j+1], aq[4*j+2], aq[4*j+3]);
    }
}

// ---------------- GEMM1 (MFMA): 64x128 tile, K-step 64, 6-product f16 split ----------------
// Grid (2, 256) = 512 blocks = 2/CU, 72KB LDS single-buffered. Per K-step each wave
// issues 96 MFMA (~460cy) between barrier pairs -- 4x the R12 ratio (R12's 64x64/K32
// version was drain-latency-bound at ~17% MfmaUtil). 16 K-iterations (was 32).
// Per-acc MFMA order identical to R12 (kt asc, ksub asc, same 6-product chain) -> h
// bit-identical. Staging pure global_load_lds, lane-linear, 1KB contiguous per op.
__global__ __launch_bounds__(256) void mlp1_mfma(const f16* __restrict__ gxh,
                                                 const f16* __restrict__ gxl,
                                                 const f16* __restrict__ gxq,
                                                 const f16* __restrict__ wth,
                                                 const f16* __restrict__ wtl,
                                                 const f16* __restrict__ wtq,
                                                 const float* __restrict__ b1,
                                                 float* __restrict__ h) {
    __shared__ __align__(16) f16 As[3][64 * 64];    // 3 x 8KB  = 24KB
    __shared__ __align__(16) f16 Bs[3][128 * 64];   // 3 x 16KB = 48KB
    const int bn = blockIdx.x;   // 2 col-tiles of 128
    const int bm = blockIdx.y;   // 256 row-tiles of 64
    const int tid = threadIdx.x;
    const int w = tid >> 6, l = tid & 63;

    const f16* pA[3] = {gxh + (size_t)(bm * 64) * DIN, gxl + (size_t)(bm * 64) * DIN,
                        gxq + (size_t)(bm * 64) * DIN};
    const f16* pB[3] = {wth + (size_t)(bn * 128) * DIN, wtl + (size_t)(bn * 128) * DIN,
                        wtq + (size_t)(bn * 128) * DIN};

    f32x4 acc[8];
#pragma unroll
    for (int ct = 0; ct < 8; ++ct) acc[ct] = (f32x4){0.f, 0.f, 0.f, 0.f};

    const int srow = l >> 3;        // 0..7 row within an 8-row glds group
    const int scol = (l & 7) * 8;   // halfword offset 0..56
    const int fr = l & 15, fk = (l >> 4) * 8;

    for (int kt = 0; kt < DIN; kt += 64) {
        __syncthreads();
#pragma unroll
        for (int s = 0; s < 3; ++s) {
            // A: wave w stages rows w*16 .. w*16+15 (2 glds of 8 rows)
#pragma unroll
            for (int g = 0; g < 2; ++g) {
                const f16* src = pA[s] + (size_t)(w * 16 + g * 8 + srow) * DIN + kt + scol;
                __builtin_amdgcn_global_load_lds(
                    (const __attribute__((address_space(1))) unsigned int*)src,
                    (__attribute__((address_space(3))) unsigned int*)&As[s][(w * 16 + g * 8) * 64],
                    16, 0, 0);
            }
            // B: wave w stages rows w*32 .. w*32+31 (4 glds of 8 rows)
#pragma unroll
            for (int g = 0; g < 4; ++g) {
                const f16* src = pB[s] + (size_t)(w * 32 + g * 8 + srow) * DIN + kt + scol;
                __builtin_amdgcn_global_load_lds(
                    (const __attribute__((address_space(1))) unsigned int*)src,
                    (__attribute__((address_space(3))) unsigned int*)&Bs[s][(w * 32 + g * 8) * 64],
                    16, 0, 0);
            }
        }
        __syncthreads();  // vmcnt(0) drain: all 6 tiles resident

#pragma unroll
        for (int ksub = 0; ksub < 2; ++ksub) {
            f16x8 Ah = *(const f16x8*)&As[0][(w * 16 + fr) * 64 + ksub * 32 + fk];
            f16x8 Al = *(const f16x8*)&As[1][(w * 16 + fr) * 64 + ksub * 32 + fk];
            f16x8 Aq = *(const f16x8*)&As[2][(w * 16 + fr) * 64 + ksub * 32 + fk];
#pragma unroll
            for (int ct = 0; ct < 8; ++ct) {
                f16x8 Bh = *(const f16x8*)&Bs[0][(ct * 16 + fr) * 64 + ksub * 32 + fk];
                f16x8 Bl = *(const f16x8*)&Bs[1][(ct * 16 + fr) * 64 + ksub * 32 + fk];
                f16x8 Bq = *(const f16x8*)&Bs[2][(ct * 16 + fr) * 64 + ksub * 32 + fk];
                f32x4 a = acc[ct];
                a = __builtin_amdgcn_mfma_f32_16x16x32_f16(Ah, Bh, a, 0, 0, 0);
                a = __builtin_amdgcn_mfma_f32_16x16x32_f16(Ah, Bl, a, 0, 0, 0);
                a = __builtin_amdgcn_mfma_f32_16x16x32_f16(Al, Bh, a, 0, 0, 0);
                a = __builtin_amdgcn_mfma_f32_16x16x32_f16(Ah, Bq, a, 0, 0, 0);
                a = __builtin_amdgcn_mfma_f32_16x16x32_f16(Aq, Bh, a, 0, 0, 0);
                a = __builtin_amdgcn_mfma_f32_16x16x32_f16(Al, Bl, a, 0, 0, 0);
                acc[ct] = a;
            }
        }
    }

    const int orow = bm * 64 + w * 16 + (l >> 4) * 4;
    const int ocol0 = bn * 128 + (l & 15);
#pragma unroll
    for (int ct = 0; ct < 8; ++ct) {
        const int col = ocol0 + ct * 16;
        const float bias = b1[col];
#pragma unroll
        for (int r = 0; r < 4; ++r)
            h[(size_t)(orow + r) * H1 + col] = acc[ct][r] + bias;
    }
}

// ---------------- GEMM1 fallback (fp32, FUSE gelu, glds-B) for small workspace ----------------
__global__ __launch_bounds__(256) void mlp1_kernel(const float* __restrict__ xin,
                                                   const float* __restrict__ W1,
                                                   const float* __restrict__ b1,
                                                   float* __restrict__ h) {
    __shared__ float As[64][68];
    __shared__ float Bs[64][64];
    const int bn = blockIdx.x;
    const int bm = blockIdx.y;
    const int tid = threadIdx.x;
    const int tx = tid & 15, ty = tid >> 4;

    float acc[4][4] = {{0.f}};
    const int arow = tid >> 2;
    const int kc = (tid & 3) * 4;
    const int wv = tid >> 6;
    const int ln = tid & 63;
    const int bkr = ln >> 4;
    const int bkc = (ln & 15) * 4;

    const float* xrow = xin + (size_t)(bm * 64 + arow) * DIN;
    const float* wbase = W1 + bn * 64;

    for (int kt = 0; kt < DIN; kt += 64) {
        float4 a0 = *(const float4*)(xrow + kt + kc);
        float4 a1 = *(const float4*)(xrow + kt + kc + 16);
        float4 a2 = *(const float4*)(xrow + kt + kc + 32);
        float4 a3 = *(const float4*)(xrow + kt + kc + 48);
        __syncthreads();
#pragma unroll
        for (int s = 0; s < 4; ++s) {
            const int kr = wv * 16 + s * 4;
            const float* g = wbase + (size_t)(kt + kr + bkr) * H1 + bkc;
            __builtin_amdgcn_global_load_lds(
                (const __attribute__((address_space(1))) unsigned int*)g,
                (__attribute__((address_space(3))) unsigned int*)&Bs[kr][0], 16, 0, 0);
        }
        As[kc + 0][arow] = gelu_exact(a0.x);
        As[kc + 1][arow] = gelu_exact(a0.y);
        As[kc + 2][arow] = gelu_exact(a0.z);
        As[kc + 3][arow] = gelu_exact(a0.w);
        As[16 + kc + 0][arow] = gelu_exact(a1.x);
        As[16 + kc + 1][arow] = gelu_exact(a1.y);
        As[16 + kc + 2][arow] = gelu_exact(a1.z);
        As[16 + kc + 3][arow] = gelu_exact(a1.w);
        As[32 + kc + 0][arow] = gelu_exact(a2.x);
        As[32 + kc + 1][arow] = gelu_exact(a2.y);
        As[32 + kc + 2][arow] = gelu_exact(a2.z);
        As[32 + kc + 3][arow] = gelu_exact(a2.w);
        As[48 + kc + 0][arow] = gelu_exact(a3.x);
        As[48 + kc + 1][arow] = gelu_exact(a3.y);
        As[48 + kc + 2][arow] = gelu_exact(a3.z);
        As[48 + kc + 3][arow] = gelu_exact(a3.w);
        __syncthreads();
#pragma unroll
        for (int kk = 0; kk < 64; ++kk) {
            float4 a = *(const float4*)&As[kk][ty * 4];
            float4 b = *(const float4*)&Bs[kk][tx * 4];
            float ar[4] = {a.x, a.y, a.z, a.w};
            float br[4] = {b.x, b.y, b.z, b.w};
#pragma unroll
            for (int i = 0; i < 4; ++i)
#pragma unroll
                for (int j = 0; j < 4; ++j)
                    acc[i][j] = fmaf(ar[i], br[j], acc[i][j]);
        }
    }

    const int row = bm * 64 + ty * 4;
    const int col = bn * 64 + tx * 4;
    float4 bias = *(const float4*)(b1 + col);
#pragma unroll
    for (int i = 0; i < 4; ++i) {
        float4 o;
        o.x = acc[i][0] + bias.x;
        o.y = acc[i][1] + bias.y;
        o.z = acc[i][2] + bias.z;
        o.w = acc[i][3] + bias.w;
        *(float4*)(h + (size_t)(row + i) * H1 + col) = o;
    }
}

// ---------------- GEMM2: feats = gelu(h) @ W2 + b2 (R7 version, verified) ----------------
__global__ __launch_bounds__(256) void mlp2_kernel(const float* __restrict__ h,
                                                   const float* __restrict__ W2,
                                                   const float* __restrict__ b2,
                                                   float* __restrict__ feats) {
    __shared__ float hs[32 * HSTR];
    __shared__ float w2s[H1 * DOUT];
    const int blk = blockIdx.x;
    const int tid = threadIdx.x;

    for (int i = tid; i < (H1 * DOUT) / 4; i += 256)
        ((float4*)w2s)[i] = ((const float4*)W2)[i];

    const float* hb = h + (size_t)blk * 32 * H1;
    const int sr = tid & 31;
    const int sk = (tid >> 5) * 32;
    const float* hrow = hb + (size_t)sr * H1 + sk;
#pragma unroll
    for (int j = 0; j < 8; ++j) {
        float4 v = ((const float4*)hrow)[j];
        hs[sr * HSTR + sk + 4 * j + 0] = gelu_exact(v.x);
        hs[sr * HSTR + sk + 4 * j + 1] = gelu_exact(v.y);
        hs[sr * HSTR + sk + 4 * j + 2] = gelu_exact(v.z);
        hs[sr * HSTR + sk + 4 * j + 3] = gelu_exact(v.w);
    }
    __syncthreads();

    const int row = tid >> 3;
    const int col4 = (tid & 7) * 4;
    const float4 bias = ((const float4*)b2)[tid & 7];
    float a0 = 0.f, a1 = 0.f, a2 = 0.f, a3 = 0.f;
    const float* hr = &hs[row * HSTR];
    for (int k = 0; k < H1; ++k) {
        float a = hr[k];
        float4 w = *(const float4*)&w2s[k * DOUT + col4];
        a0 = fmaf(a, w.x, a0);
        a1 = fmaf(a, w.y, a1);
        a2 = fmaf(a, w.z, a2);
        a3 = fmaf(a, w.w, a3);
    }
    float4 o;
    o.x = a0 + bias.x;
    o.y = a1 + bias.y;
    o.z = a2 + bias.z;
    o.w = a3 + bias.w;
    *(float4*)(feats + (size_t)(blk * 32 + row) * DOUT + col4) = o;
}

// ---------------- Ward clustering: Lance-Williams recurrence (R10, verified) ----------------
__global__ __launch_bounds__(256) void ward_kernel(const float* __restrict__ feats,
                                                   int* __restrict__ out) {
    __shared__ __align__(16) float cost[NPTS * RSTR];  // 67.6 KB
    __shared__ float centsT[32 * CSTR];                // init staging only
    __shared__ unsigned long long rowkey[NPTS];
    __shared__ float sqArr[NPTS];
    __shared__ float szsE[NPTS];
    __shared__ int rnk[NPTS];

    const int b = blockIdx.x;
    const int tid = threadIdx.x;
    const float* f = feats + (size_t)b * NPTS * DOUT;
    const float INF = __builtin_inff();

    // ---- init (all 4 waves) ----
    for (int i = tid; i < NPTS * DOUT; i += 256) {
        int r = i >> 5, d = i & 31;
        centsT[d * CSTR + r] = f[i];
    }
    __syncthreads();
    if (tid < NPTS) {
        float s = 0.f;
#pragma unroll
        for (int d = 0; d < 32; ++d) {
            float v = centsT[d * CSTR + tid];
            s = fmaf(v, v, s);
        }
        sqArr[tid] = s;
    }
    __syncthreads();
    {
        int ti = tid >> 4, tj = tid & 15;
        int I0 = ti * 8, J0 = tj * 8;
        float acc[8][8];
#pragma unroll
        for (int u = 0; u < 8; ++u)
#pragma unroll
            for (int v = 0; v < 8; ++v) acc[u][v] = 0.f;
        for (int d = 0; d < 32; ++d) {
            float a[8], bb[8];
#pragma unroll
            for (int u = 0; u < 8; ++u) a[u] = centsT[d * CSTR + I0 + u];
#pragma unroll
            for (int v = 0; v < 8; ++v) bb[v] = centsT[d * CSTR + J0 + v];
#pragma unroll
            for (int u = 0; u < 8; ++u)
#pragma unroll
                for (int v = 0; v < 8; ++v)
                    acc[u][v] = fmaf(a[u], bb[v], acc[u][v]);
        }
#pragma unroll
        for (int u = 0; u < 8; ++u) {
#pragma unroll
            for (int v = 0; v < 8; ++v) {
                int i = I0 + u, j = J0 + v;
                float d2 = sqArr[i] + sqArr[j] - 2.0f * acc[u][v];
                if (d2 < 0.f) d2 = 0.f;
                float w = (1.0f * 1.0f) / (1.0f + 1.0f + 1e-30f);
                cost[i * RSTR + j] = (i == j) ? INF : w * d2;
            }
        }
    }
    __syncthreads();
    if (tid < NPTS) {
        unsigned long long best = DEADKEY;
        for (int j = 0; j < NPTS; ++j) {
            float v = cost[tid * RSTR + j];
            unsigned long long k = mkkey(v, tid, j);
            if (k < best) best = k;
        }
        rowkey[tid] = best;
    }
    __syncthreads();

    if (tid >= 64) return;  // wave 0 only
    const int lane = tid;
    const int hh = lane & 31;
    const int r0 = lane * 2, r1 = lane * 2 + 1;

    unsigned long long k0 = rowkey[r0], k1 = rowkey[r1];
    float s0 = 1.0f, s1 = 1.0f;
    int lab0 = r0, lab1 = r1;
    unsigned long long alive0 = ~0ull, alive1 = ~0ull;

    for (int it = 0; it < NPTS - KCL; ++it) {
        unsigned bv0 = (unsigned)(k0 >> 32), bv1 = (unsigned)(k1 >> 32);
        unsigned lmin = bv0 < bv1 ? bv0 : bv1;
        unsigned lflat = (bv0 <= bv1) ? (unsigned)(k0 & 0x3FFFu) : (unsigned)(k1 & 0x3FFFu);
        unsigned gmin = wave_umin_bcast(lmin);
        unsigned long long bmask = __ballot(lmin == gmin);
        int lsel = __ffsll(bmask) - 1;
        unsigned flat = (unsigned)__builtin_amdgcn_readlane((int)lflat, lsel);
        int ra = (int)(flat >> 7), ca = (int)(flat & 127u);
        const int i2 = ra < ca ? ra : ca;
        const int j2 = ra < ca ? ca : ra;
        const float Dij = __uint_as_float(gmin);

        float2 ci = *(const float2*)&cost[i2 * RSTR + r0];
        float2 cj = *(const float2*)&cost[j2 * RSTR + r0];

        float si = readlanef((i2 & 1) ? s1 : s0, i2 >> 1);
        float sj = readlanef((j2 & 1) ? s1 : s0, j2 >> 1);
        const float snew = si + sj;

        int arg0 = (int)(k0 & 127u), arg1 = (int)(k1 & 127u);
        bool d0 = (s0 > 0.f) && r0 != i2 && r0 != j2 && (arg0 == i2 || arg0 == j2);
        bool d1 = (s1 > 0.f) && r1 != i2 && r1 != j2 && (arg1 == i2 || arg1 == j2);
        unsigned long long m0 = __ballot(d0), m1 = __ballot(d1);

        float Dn0 = ((si + s0) * ci.x + (sj + s0) * cj.x - s0 * Dij) / (snew + s0);
        float Dn1 = ((si + s1) * ci.y + (sj + s1) * cj.y - s1 * Dij) / (snew + s1);
        if (Dn0 < 0.f) Dn0 = 0.f;
        if (Dn1 < 0.f) Dn1 = 0.f;

        if (lab0 == j2) lab0 = i2;
        if (lab1 == j2) lab1 = i2;
        if (r0 == i2) s0 = snew; else if (r0 == j2) { s0 = 0.f; k0 = DEADKEY; }
        if (r1 == i2) s1 = snew; else if (r1 == j2) { s1 = 0.f; k1 = DEADKEY; }
        if (j2 < 64) alive0 &= ~(1ull << j2); else alive1 &= ~(1ull << (j2 - 64));

        bool w0 = (s0 > 0.f) && r0 != i2 && r0 != j2;
        bool w1 = (s1 > 0.f) && r1 != i2 && r1 != j2;
        if (w0) {
            cost[r0 * RSTR + i2] = Dn0;
            cost[i2 * RSTR + r0] = Dn0;
            if (!d0) {
                unsigned long long nk = mkkey(Dn0, r0, i2);
                if (nk < k0) k0 = nk;
            }
        }
        if (w1) {
            cost[r1 * RSTR + i2] = Dn1;
            cost[i2 * RSTR + r1] = Dn1;
            if (!d1) {
                unsigned long long nk = mkkey(Dn1, r1, i2);
                if (nk < k1) k1 = nk;
            }
        }

        bool pi = true;
        unsigned long long mm0 = m0, mm1 = m1;
        while (pi | (mm0 != 0ull) | (mm1 != 0ull)) {
            int rA, rB;
            bool hasB = false;
            if (pi) { rA = i2; pi = false; }
            else if (mm0) { int t = __ffsll(mm0) - 1; rA = 2 * t; mm0 &= mm0 - 1; }
            else { int t = __ffsll(mm1) - 1; rA = 2 * t + 1; mm1 &= mm1 - 1; }
            if (mm0) { int t = __ffsll(mm0) - 1; rB = 2 * t; mm0 &= mm0 - 1; hasB = true; }
            else if (mm1) { int t = __ffsll(mm1) - 1; rB = 2 * t + 1; mm1 &= mm1 - 1; hasB = true; }
            else rB = rA;

            int r = (lane < 32) ? rA : rB;
            float4 cv = *(const float4*)&cost[r * RSTR + 4 * hh];
            unsigned long long word = (hh < 16) ? alive0 : alive1;
            unsigned nib = (unsigned)(word >> ((4 * hh) & 63)) & 0xFu;
            unsigned e0 = (nib & 1u) ? __float_as_uint(cv.x) : 0xFFFFFFFFu;
            unsigned e1 = (nib & 2u) ? __float_as_uint(cv.y) : 0xFFFFFFFFu;
            unsigned e2 = (nib & 4u) ? __float_as_uint(cv.z) : 0xFFFFFFFFu;
            unsigned e3 = (nib & 8u) ? __float_as_uint(cv.w) : 0xFFFFFFFFu;
            unsigned m = e0; int c = 0;
            if (e1 < m) { m = e1; c = 1; }
            if (e2 < m) { m = e2; c = 2; }
            if (e3 < m) { m = e3; c = 3; }
            int lcol = 4 * hh + c;
            unsigned hm = half_umin(m);
            unsigned vA = (unsigned)__builtin_amdgcn_readlane((int)hm, 31);
            unsigned vB = (unsigned)__builtin_amdgcn_readlane((int)hm, 63);
            unsigned vref = (lane < 32) ? vA : vB;
            unsigned long long msk = __ballot(m == vref);
            int laneA = __ffsll(msk & 0xFFFFFFFFull) - 1;
            int laneB = 32 + __ffsll(msk >> 32) - 1;
            int colA = __builtin_amdgcn_readlane(lcol, laneA);
            int colB = __builtin_amdgcn_readlane(lcol, laneB);
            unsigned long long keyA = ((unsigned long long)vA << 32) | (unsigned)((rA << 7) | colA);
            unsigned long long keyB = ((unsigned long long)vB << 32) | (unsigned)((rB << 7) | colB);
            if (lane == (rA >> 1)) { if (rA & 1) k1 = keyA; else k0 = keyA; }
            if (hasB && lane == (rB >> 1)) { if (rB & 1) k1 = keyB; else k0 = keyB; }
        }
    }

    szsE[r0] = s0;
    szsE[r1] = s1;
    __asm__ volatile("s_waitcnt lgkmcnt(0)" ::: "memory");
    if (lane == 0) {
        int c = 0;
        for (int i = 0; i < NPTS; ++i) rnk[i] = (szsE[i] > 0.f) ? c++ : -1;
    }
    __asm__ volatile("s_waitcnt lgkmcnt(0)" ::: "memory");
    out[b * NPTS + r0] = rnk[lab0];
    out[b * NPTS + r1] = rnk[lab1];
}

extern "C" void kernel_launch(void* const* d_in, const int* in_sizes, int n_in,
                              void* d_out, int out_size, void* d_ws, size_t ws_size,
                              hipStream_t stream) {
    const float* x  = (const float*)d_in[0];
    const float* W1 = (const float*)d_in[1];
    const float* b1 = (const float*)d_in[2];
    const float* W2 = (const float*)d_in[3];
    const float* b2 = (const float*)d_in[4];
    int* out = (int*)d_out;

    float* h = (float*)d_ws;                                   // 16.8 MB
    float* feats = h + (size_t)MROWS * H1;                     // 2.1 MB
    unsigned short* gxh = (unsigned short*)(feats + (size_t)MROWS * DOUT);
    unsigned short* gxl = gxh + (size_t)MROWS * DIN;           // 33.6 MB each
    unsigned short* gxq = gxl + (size_t)MROWS * DIN;
    unsigned short* wth = gxq + (size_t)MROWS * DIN;           // 0.52 MB each
    unsigned short* wtl = wth + (size_t)H1 * DIN;
    unsigned short* wtq = wtl + (size_t)H1 * DIN;

    const size_t need_mfma = ((size_t)MROWS * H1 + (size_t)MROWS * DOUT) * 4 +
                             (size_t)MROWS * DIN * 2 * 3 + (size_t)H1 * DIN * 2 * 3;

    if (ws_size >= need_mfma) {
        prep_kernel<<<2048, 256, 0, stream>>>(x, gxh, gxl, gxq, MROWS * DIN / 4);
        w1prep_kernel<<<64, 256, 0, stream>>>(W1, wth, wtl, wtq);
        mlp1_mfma<<<dim3(2, 256), 256, 0, stream>>>(
            (const f16*)gxh, (const f16*)gxl, (const f16*)gxq,
            (const f16*)wth, (const f16*)wtl, (const f16*)wtq, b1, h);
    } else {
        mlp1_kernel<<<dim3(4, 256), 256, 0, stream>>>(x, W1, b1, h);
    }
    mlp2_kernel<<<MROWS / 32, 256, 0, stream>>>(h, W2, b2, feats);
    ward_kernel<<<BB, 256, 0, stream>>>(feats, out);
}

// Round 14
// 366.869 us; speedup vs baseline: 1.2159x; 1.0469x over previous
//
#include <hip/hip_runtime.h>
#include <math.h>

#define BB 128
#define NN 128
#define DIN 1024
#define H1 256
#define DOUT 32
#define KCL 8
#define NPTS 128
#define MROWS (BB*NN)   // 16384
#define CSTR 130        // centsT row stride (words, init staging only)
#define RSTR 132        // cost row stride (words, 16B aligned)
#define HSTR 257        // mlp2 h-chunk row stride (odd -> conflict-free reads)
#define DEADKEY 0xFFFFFFFF00000000ull

typedef _Float16 f16;
typedef f16 f16x8 __attribute__((ext_vector_type(8)));
typedef float f32x4 __attribute__((ext_vector_type(4)));

__device__ __forceinline__ float gelu_exact(float v) {
    return 0.5f * v * (1.0f + erff(v * 0.70710678118654752f));
}

__device__ __forceinline__ unsigned long long mkkey(float v, int r, int j) {
    return ((unsigned long long)__float_as_uint(v) << 32) | (unsigned)((r << 7) | j);
}

__device__ __forceinline__ float readlanef(float v, int lane) {
    return __int_as_float(__builtin_amdgcn_readlane(__float_as_int(v), lane));
}

// u32 min via DPP (costs are >=0 floats: IEEE order == unsigned bit order)
template<int CTRL, int RMASK>
__device__ __forceinline__ unsigned dpp_umin_step(unsigned v) {
    unsigned t = (unsigned)__builtin_amdgcn_update_dpp((int)v, (int)v, CTRL, RMASK, 0xf, false);
    return t < v ? t : v;
}
__device__ __forceinline__ unsigned wave_umin_bcast(unsigned v) {
    v = dpp_umin_step<0x111, 0xf>(v);
    v = dpp_umin_step<0x112, 0xf>(v);
    v = dpp_umin_step<0x114, 0xf>(v);
    v = dpp_umin_step<0x118, 0xf>(v);
    v = dpp_umin_step<0x142, 0xa>(v);
    v = dpp_umin_step<0x143, 0xc>(v);
    return (unsigned)__builtin_amdgcn_readlane((int)v, 63);
}
// lane31 = min(lanes0..31), lane63 = min(lanes32..63)
__device__ __forceinline__ unsigned half_umin(unsigned v) {
    v = dpp_umin_step<0x111, 0xf>(v);
    v = dpp_umin_step<0x112, 0xf>(v);
    v = dpp_umin_step<0x114, 0xf>(v);
    v = dpp_umin_step<0x118, 0xf>(v);
    v = dpp_umin_step<0x142, 0xa>(v);
    return v;
}

// 3-way f16 split: g = h + l + q with residual ~|g|*2^-33 (or < f16 subnormal floor)
__device__ __forceinline__ void split3(float g, unsigned short &uh, unsigned short &ul,
                                       unsigned short &uq) {
    f16 h = (f16)g;
    float r = g - (float)h;
    f16 l = (f16)r;
    float r2 = r - (float)l;
    f16 q = (f16)r2;
    uh = __builtin_bit_cast(unsigned short, h);
    ul = __builtin_bit_cast(unsigned short, l);
    uq = __builtin_bit_cast(unsigned short, q);
}

// ---------------- prep: gxh/l/q = split3(gelu(x)), memory-bound ----------------
__global__ __launch_bounds__(256) void prep_kernel(const float* __restrict__ x,
                                                   unsigned short* __restrict__ gh,
                                                   unsigned short* __restrict__ gl,
                                                   unsigned short* __restrict__ gq, int n4) {
    int i = blockIdx.x * 256 + threadIdx.x;
    const int stride = gridDim.x * 256;
    for (; i < n4; i += stride) {
        float4 v = ((const float4*)x)[i];
        ushort4 oh, ol, oq;
        split3(gelu_exact(v.x), oh.x, ol.x, oq.x);
        split3(gelu_exact(v.y), oh.y, ol.y, oq.y);
        split3(gelu_exact(v.z), oh.z, ol.z, oq.z);
        split3(gelu_exact(v.w), oh.w, ol.w, oq.w);
        ((ushort4*)gh)[i] = oh;
        ((ushort4*)gl)[i] = ol;
        ((ushort4*)gq)[i] = oq;
    }
}

// ---------------- w1prep: W1 [K][N] fp32 -> W1T h/l/q [N][K] f16 (one-time, 1MB) ----------------
__global__ __launch_bounds__(256) void w1prep_kernel(const float* __restrict__ W1,
                                                     unsigned short* __restrict__ th,
                                                     unsigned short* __restrict__ tl,
                                                     unsigned short* __restrict__ tq) {
    const int n = blockIdx.x * 4 + (threadIdx.x >> 6);  // 64 blocks x 4 = 256
    const int t = threadIdx.x & 63;                     // k-group: k = t*16 + i
    unsigned short ah[16], al[16], aq[16];
#pragma unroll
    for (int i = 0; i < 16; ++i) {
        int k = t * 16 + i;
        split3(W1[(size_t)k * H1 + n], ah[i], al[i], aq[i]);
    }
    const size_t base = (size_t)n * DIN + t * 16;
#pragma unroll
    for (int j = 0; j < 4; ++j) {
        *(ushort4*)(th + base + 4 * j) = make_ushort4(ah[4*j], ah[4*j+1], ah[4*j+2], ah[4*j+3]);
        *(ushort4*)(tl + base + 4 * j) = make_ushort4(al[4*j], al[4*j+1], al[4*j+2], al[4*j+3]);
        *(ushort4*)(tq + base + 4 * j) = make_ushort4(aq[4*j], aq[4*j+1], aq[4*j+2], aq[4*j+3]);
    }
}

// ---------------- GEMM1 (MFMA): 64x128 tile, K-step 64, 6-product f16 split ----------------
// R14 change: XOR-swizzled LDS tiles (T2). R13's fragment reads (lanes 0-15 at row
// stride 128B) were a 16-WAY BANK CONFLICT on every A/B b128 load -- 54 conflicted
// reads/wave/K-step dwarfed the 96 MFMA; that's the measured ~125us. Fix per m201's
// both-sides-or-neither: global_load_lds dest stays LINEAR; the global SOURCE is
// pre-swizzled per lane (granule p holds logical p^(row&7), XOR = involution), and
// fragment reads XOR the granule with (row&7). Lanes 0-15 now hit 8 distinct granules
// x 2 rows = 2-way = free (m136). Same values, same MFMA order -> h bit-identical.
__global__ __launch_bounds__(256) void mlp1_mfma(const f16* __restrict__ gxh,
                                                 const f16* __restrict__ gxl,
                                                 const f16* __restrict__ gxq,
                                                 const f16* __restrict__ wth,
                                                 const f16* __restrict__ wtl,
                                                 const f16* __restrict__ wtq,
                                                 const float* __restrict__ b1,
                                                 float* __restrict__ h) {
    __shared__ __align__(16) f16 As[3][64 * 64];    // 3 x 8KB  = 24KB
    __shared__ __align__(16) f16 Bs[3][128 * 64];   // 3 x 16KB = 48KB
    const int bn = blockIdx.x;   // 2 col-tiles of 128
    const int bm = blockIdx.y;   // 256 row-tiles of 64
    const int tid = threadIdx.x;
    const int w = tid >> 6, l = tid & 63;

    const f16* pA[3] = {gxh + (size_t)(bm * 64) * DIN, gxl + (size_t)(bm * 64) * DIN,
                        gxq + (size_t)(bm * 64) * DIN};
    const f16* pB[3] = {wth + (size_t)(bn * 128) * DIN, wtl + (size_t)(bn * 128) * DIN,
                        wtq + (size_t)(bn * 128) * DIN};

    f32x4 acc[8];
#pragma unroll
    for (int ct = 0; ct < 8; ++ct) acc[ct] = (f32x4){0.f, 0.f, 0.f, 0.f};

    const int srow = l >> 3;              // 0..7 row within an 8-row glds group
    const int scol = ((l & 7) ^ srow) * 8;  // SWIZZLED source granule (halfword offset)
    const int fr = l & 15;
    const int f7 = fr & 7;                // read-side swizzle key (row & 7)

    for (int kt = 0; kt < DIN; kt += 64) {
        __syncthreads();
#pragma unroll
        for (int s = 0; s < 3; ++s) {
            // A: wave w stages rows w*16 .. w*16+15 (2 glds of 8 rows), swizzled source
#pragma unroll
            for (int g = 0; g < 2; ++g) {
                const f16* src = pA[s] + (size_t)(w * 16 + g * 8 + srow) * DIN + kt + scol;
                __builtin_amdgcn_global_load_lds(
                    (const __attribute__((address_space(1))) unsigned int*)src,
                    (__attribute__((address_space(3))) unsigned int*)&As[s][(w * 16 + g * 8) * 64],
                    16, 0, 0);
            }
            // B: wave w stages rows w*32 .. w*32+31 (4 glds of 8 rows), swizzled source
#pragma unroll
            for (int g = 0; g < 4; ++g) {
                const f16* src = pB[s] + (size_t)(w * 32 + g * 8 + srow) * DIN + kt + scol;
                __builtin_amdgcn_global_load_lds(
                    (const __attribute__((address_space(1))) unsigned int*)src,
                    (__attribute__((address_space(3))) unsigned int*)&Bs[s][(w * 32 + g * 8) * 64],
                    16, 0, 0);
            }
        }
        __syncthreads();  // vmcnt(0) drain: all 6 tiles resident

#pragma unroll
        for (int ksub = 0; ksub < 2; ++ksub) {
            const int po = ((ksub * 4 + (l >> 4)) ^ f7) * 8;  // swizzled phys offset
            f16x8 Ah = *(const f16x8*)&As[0][(w * 16 + fr) * 64 + po];
            f16x8 Al = *(const f16x8*)&As[1][(w * 16 + fr) * 64 + po];
            f16x8 Aq = *(const f16x8*)&As[2][(w * 16 + fr) * 64 + po];
#pragma unroll
            for (int ct = 0; ct < 8; ++ct) {
                f16x8 Bh = *(const f16x8*)&Bs[0][(ct * 16 + fr) * 64 + po];
                f16x8 Bl = *(const f16x8*)&Bs[1][(ct * 16 + fr) * 64 + po];
                f16x8 Bq = *(const f16x8*)&Bs[2][(ct * 16 + fr) * 64 + po];
                f32x4 a = acc[ct];
                a = __builtin_amdgcn_mfma_f32_16x16x32_f16(Ah, Bh, a, 0, 0, 0);
                a = __builtin_amdgcn_mfma_f32_16x16x32_f16(Ah, Bl, a, 0, 0, 0);
                a = __builtin_amdgcn_mfma_f32_16x16x32_f16(Al, Bh, a, 0, 0, 0);
                a = __builtin_amdgcn_mfma_f32_16x16x32_f16(Ah, Bq, a, 0, 0, 0);
                a = __builtin_amdgcn_mfma_f32_16x16x32_f16(Aq, Bh, a, 0, 0, 0);
                a = __builtin_amdgcn_mfma_f32_16x16x32_f16(Al, Bl, a, 0, 0, 0);
                acc[ct] = a;
            }
        }
    }

    const int orow = bm * 64 + w * 16 + (l >> 4) * 4;
    const int ocol0 = bn * 128 + (l & 15);
#pragma unroll
    for (int ct = 0; ct < 8; ++ct) {
        const int col = ocol0 + ct * 16;
        const float bias = b1[col];
#pragma unroll
        for (int r = 0; r < 4; ++r)
            h[(size_t)(orow + r) * H1 + col] = acc[ct][r] + bias;
    }
}

// ---------------- GEMM1 fallback (fp32, FUSE gelu, glds-B) for small workspace ----------------
__global__ __launch_bounds__(256) void mlp1_kernel(const float* __restrict__ xin,
                                                   const float* __restrict__ W1,
                                                   const float* __restrict__ b1,
                                                   float* __restrict__ h) {
    __shared__ float As[64][68];
    __shared__ float Bs[64][64];
    const int bn = blockIdx.x;
    const int bm = blockIdx.y;
    const int tid = threadIdx.x;
    const int tx = tid & 15, ty = tid >> 4;

    float acc[4][4] = {{0.f}};
    const int arow = tid >> 2;
    const int kc = (tid & 3) * 4;
    const int wv = tid >> 6;
    const int ln = tid & 63;
    const int bkr = ln >> 4;
    const int bkc = (ln & 15) * 4;

    const float* xrow = xin + (size_t)(bm * 64 + arow) * DIN;
    const float* wbase = W1 + bn * 64;

    for (int kt = 0; kt < DIN; kt += 64) {
        float4 a0 = *(const float4*)(xrow + kt + kc);
        float4 a1 = *(const float4*)(xrow + kt + kc + 16);
        float4 a2 = *(const float4*)(xrow + kt + kc + 32);
        float4 a3 = *(const float4*)(xrow + kt + kc + 48);
        __syncthreads();
#pragma unroll
        for (int s = 0; s < 4; ++s) {
            const int kr = wv * 16 + s * 4;
            const float* g = wbase + (size_t)(kt + kr + bkr) * H1 + bkc;
            __builtin_amdgcn_global_load_lds(
                (const __attribute__((address_space(1))) unsigned int*)g,
                (__attribute__((address_space(3))) unsigned int*)&Bs[kr][0], 16, 0, 0);
        }
        As[kc + 0][arow] = gelu_exact(a0.x);
        As[kc + 1][arow] = gelu_exact(a0.y);
        As[kc + 2][arow] = gelu_exact(a0.z);
        As[kc + 3][arow] = gelu_exact(a0.w);
        As[16 + kc + 0][arow] = gelu_exact(a1.x);
        As[16 + kc + 1][arow] = gelu_exact(a1.y);
        As[16 + kc + 2][arow] = gelu_exact(a1.z);
        As[16 + kc + 3][arow] = gelu_exact(a1.w);
        As[32 + kc + 0][arow] = gelu_exact(a2.x);
        As[32 + kc + 1][arow] = gelu_exact(a2.y);
        As[32 + kc + 2][arow] = gelu_exact(a2.z);
        As[32 + kc + 3][arow] = gelu_exact(a2.w);
        As[48 + kc + 0][arow] = gelu_exact(a3.x);
        As[48 + kc + 1][arow] = gelu_exact(a3.y);
        As[48 + kc + 2][arow] = gelu_exact(a3.z);
        As[48 + kc + 3][arow] = gelu_exact(a3.w);
        __syncthreads();
#pragma unroll
        for (int kk = 0; kk < 64; ++kk) {
            float4 a = *(const float4*)&As[kk][ty * 4];
            float4 b = *(const float4*)&Bs[kk][tx * 4];
            float ar[4] = {a.x, a.y, a.z, a.w};
            float br[4] = {b.x, b.y, b.z, b.w};
#pragma unroll
            for (int i = 0; i < 4; ++i)
#pragma unroll
                for (int j = 0; j < 4; ++j)
                    acc[i][j] = fmaf(ar[i], br[j], acc[i][j]);
        }
    }

    const int row = bm * 64 + ty * 4;
    const int col = bn * 64 + tx * 4;
    float4 bias = *(const float4*)(b1 + col);
#pragma unroll
    for (int i = 0; i < 4; ++i) {
        float4 o;
        o.x = acc[i][0] + bias.x;
        o.y = acc[i][1] + bias.y;
        o.z = acc[i][2] + bias.z;
        o.w = acc[i][3] + bias.w;
        *(float4*)(h + (size_t)(row + i) * H1 + col) = o;
    }
}

// ---------------- GEMM2: feats = gelu(h) @ W2 + b2 (R7 version, verified) ----------------
__global__ __launch_bounds__(256) void mlp2_kernel(const float* __restrict__ h,
                                                   const float* __restrict__ W2,
                                                   const float* __restrict__ b2,
                                                   float* __restrict__ feats) {
    __shared__ float hs[32 * HSTR];
    __shared__ float w2s[H1 * DOUT];
    const int blk = blockIdx.x;
    const int tid = threadIdx.x;

    for (int i = tid; i < (H1 * DOUT) / 4; i += 256)
        ((float4*)w2s)[i] = ((const float4*)W2)[i];

    const float* hb = h + (size_t)blk * 32 * H1;
    const int sr = tid & 31;
    const int sk = (tid >> 5) * 32;
    const float* hrow = hb + (size_t)sr * H1 + sk;
#pragma unroll
    for (int j = 0; j < 8; ++j) {
        float4 v = ((const float4*)hrow)[j];
        hs[sr * HSTR + sk + 4 * j + 0] = gelu_exact(v.x);
        hs[sr * HSTR + sk + 4 * j + 1] = gelu_exact(v.y);
        hs[sr * HSTR + sk + 4 * j + 2] = gelu_exact(v.z);
        hs[sr * HSTR + sk + 4 * j + 3] = gelu_exact(v.w);
    }
    __syncthreads();

    const int row = tid >> 3;
    const int col4 = (tid & 7) * 4;
    const float4 bias = ((const float4*)b2)[tid & 7];
    float a0 = 0.f, a1 = 0.f, a2 = 0.f, a3 = 0.f;
    const float* hr = &hs[row * HSTR];
    for (int k = 0; k < H1; ++k) {
        float a = hr[k];
        float4 w = *(const float4*)&w2s[k * DOUT + col4];
        a0 = fmaf(a, w.x, a0);
        a1 = fmaf(a, w.y, a1);
        a2 = fmaf(a, w.z, a2);
        a3 = fmaf(a, w.w, a3);
    }
    float4 o;
    o.x = a0 + bias.x;
    o.y = a1 + bias.y;
    o.z = a2 + bias.z;
    o.w = a3 + bias.w;
    *(float4*)(feats + (size_t)(blk * 32 + row) * DOUT + col4) = o;
}

// ---------------- Ward clustering: Lance-Williams recurrence (R10, verified) ----------------
__global__ __launch_bounds__(256) void ward_kernel(const float* __restrict__ feats,
                                                   int* __restrict__ out) {
    __shared__ __align__(16) float cost[NPTS * RSTR];  // 67.6 KB
    __shared__ float centsT[32 * CSTR];                // init staging only
    __shared__ unsigned long long rowkey[NPTS];
    __shared__ float sqArr[NPTS];
    __shared__ float szsE[NPTS];
    __shared__ int rnk[NPTS];

    const int b = blockIdx.x;
    const int tid = threadIdx.x;
    const float* f = feats + (size_t)b * NPTS * DOUT;
    const float INF = __builtin_inff();

    // ---- init (all 4 waves) ----
    for (int i = tid; i < NPTS * DOUT; i += 256) {
        int r = i >> 5, d = i & 31;
        centsT[d * CSTR + r] = f[i];
    }
    __syncthreads();
    if (tid < NPTS) {
        float s = 0.f;
#pragma unroll
        for (int d = 0; d < 32; ++d) {
            float v = centsT[d * CSTR + tid];
            s = fmaf(v, v, s);
        }
        sqArr[tid] = s;
    }
    __syncthreads();
    {
        int ti = tid >> 4, tj = tid & 15;
        int I0 = ti * 8, J0 = tj * 8;
        float acc[8][8];
#pragma unroll
        for (int u = 0; u < 8; ++u)
#pragma unroll
            for (int v = 0; v < 8; ++v) acc[u][v] = 0.f;
        for (int d = 0; d < 32; ++d) {
            float a[8], bb[8];
#pragma unroll
            for (int u = 0; u < 8; ++u) a[u] = centsT[d * CSTR + I0 + u];
#pragma unroll
            for (int v = 0; v < 8; ++v) bb[v] = centsT[d * CSTR + J0 + v];
#pragma unroll
            for (int u = 0; u < 8; ++u)
#pragma unroll
                for (int v = 0; v < 8; ++v)
                    acc[u][v] = fmaf(a[u], bb[v], acc[u][v]);
        }
#pragma unroll
        for (int u = 0; u < 8; ++u) {
#pragma unroll
            for (int v = 0; v < 8; ++v) {
                int i = I0 + u, j = J0 + v;
                float d2 = sqArr[i] + sqArr[j] - 2.0f * acc[u][v];
                if (d2 < 0.f) d2 = 0.f;
                float w = (1.0f * 1.0f) / (1.0f + 1.0f + 1e-30f);
                cost[i * RSTR + j] = (i == j) ? INF : w * d2;
            }
        }
    }
    __syncthreads();
    if (tid < NPTS) {
        unsigned long long best = DEADKEY;
        for (int j = 0; j < NPTS; ++j) {
            float v = cost[tid * RSTR + j];
            unsigned long long k = mkkey(v, tid, j);
            if (k < best) best = k;
        }
        rowkey[tid] = best;
    }
    __syncthreads();

    if (tid >= 64) return;  // wave 0 only
    const int lane = tid;
    const int hh = lane & 31;
    const int r0 = lane * 2, r1 = lane * 2 + 1;

    unsigned long long k0 = rowkey[r0], k1 = rowkey[r1];
    float s0 = 1.0f, s1 = 1.0f;
    int lab0 = r0, lab1 = r1;
    unsigned long long alive0 = ~0ull, alive1 = ~0ull;

    for (int it = 0; it < NPTS - KCL; ++it) {
        unsigned bv0 = (unsigned)(k0 >> 32), bv1 = (unsigned)(k1 >> 32);
        unsigned lmin = bv0 < bv1 ? bv0 : bv1;
        unsigned lflat = (bv0 <= bv1) ? (unsigned)(k0 & 0x3FFFu) : (unsigned)(k1 & 0x3FFFu);
        unsigned gmin = wave_umin_bcast(lmin);
        unsigned long long bmask = __ballot(lmin == gmin);
        int lsel = __ffsll(bmask) - 1;
        unsigned flat = (unsigned)__builtin_amdgcn_readlane((int)lflat, lsel);
        int ra = (int)(flat >> 7), ca = (int)(flat & 127u);
        const int i2 = ra < ca ? ra : ca;
        const int j2 = ra < ca ? ca : ra;
        const float Dij = __uint_as_float(gmin);

        float2 ci = *(const float2*)&cost[i2 * RSTR + r0];
        float2 cj = *(const float2*)&cost[j2 * RSTR + r0];

        float si = readlanef((i2 & 1) ? s1 : s0, i2 >> 1);
        float sj = readlanef((j2 & 1) ? s1 : s0, j2 >> 1);
        const float snew = si + sj;

        int arg0 = (int)(k0 & 127u), arg1 = (int)(k1 & 127u);
        bool d0 = (s0 > 0.f) && r0 != i2 && r0 != j2 && (arg0 == i2 || arg0 == j2);
        bool d1 = (s1 > 0.f) && r1 != i2 && r1 != j2 && (arg1 == i2 || arg1 == j2);
        unsigned long long m0 = __ballot(d0), m1 = __ballot(d1);

        float Dn0 = ((si + s0) * ci.x + (sj + s0) * cj.x - s0 * Dij) / (snew + s0);
        float Dn1 = ((si + s1) * ci.y + (sj + s1) * cj.y - s1 * Dij) / (snew + s1);
        if (Dn0 < 0.f) Dn0 = 0.f;
        if (Dn1 < 0.f) Dn1 = 0.f;

        if (lab0 == j2) lab0 = i2;
        if (lab1 == j2) lab1 = i2;
        if (r0 == i2) s0 = snew; else if (r0 == j2) { s0 = 0.f; k0 = DEADKEY; }
        if (r1 == i2) s1 = snew; else if (r1 == j2) { s1 = 0.f; k1 = DEADKEY; }
        if (j2 < 64) alive0 &= ~(1ull << j2); else alive1 &= ~(1ull << (j2 - 64));

        bool w0 = (s0 > 0.f) && r0 != i2 && r0 != j2;
        bool w1 = (s1 > 0.f) && r1 != i2 && r1 != j2;
        if (w0) {
            cost[r0 * RSTR + i2] = Dn0;
            cost[i2 * RSTR + r0] = Dn0;
            if (!d0) {
                unsigned long long nk = mkkey(Dn0, r0, i2);
                if (nk < k0) k0 = nk;
            }
        }
        if (w1) {
            cost[r1 * RSTR + i2] = Dn1;
            cost[i2 * RSTR + r1] = Dn1;
            if (!d1) {
                unsigned long long nk = mkkey(Dn1, r1, i2);
                if (nk < k1) k1 = nk;
            }
        }

        bool pi = true;
        unsigned long long mm0 = m0, mm1 = m1;
        while (pi | (mm0 != 0ull) | (mm1 != 0ull)) {
            int rA, rB;
            bool hasB = false;
            if (pi) { rA = i2; pi = false; }
            else if (mm0) { int t = __ffsll(mm0) - 1; rA = 2 * t; mm0 &= mm0 - 1; }
            else { int t = __ffsll(mm1) - 1; rA = 2 * t + 1; mm1 &= mm1 - 1; }
            if (mm0) { int t = __ffsll(mm0) - 1; rB = 2 * t; mm0 &= mm0 - 1; hasB = true; }
            else if (mm1) { int t = __ffsll(mm1) - 1; rB = 2 * t + 1; mm1 &= mm1 - 1; hasB = true; }
            else rB = rA;

            int r = (lane < 32) ? rA : rB;
            float4 cv = *(const float4*)&cost[r * RSTR + 4 * hh];
            unsigned long long word = (hh < 16) ? alive0 : alive1;
            unsigned nib = (unsigned)(word >> ((4 * hh) & 63)) & 0xFu;
            unsigned e0 = (nib & 1u) ? __float_as_uint(cv.x) : 0xFFFFFFFFu;
            unsigned e1 = (nib & 2u) ? __float_as_uint(cv.y) : 0xFFFFFFFFu;
            unsigned e2 = (nib & 4u) ? __float_as_uint(cv.z) : 0xFFFFFFFFu;
            unsigned e3 = (nib & 8u) ? __float_as_uint(cv.w) : 0xFFFFFFFFu;
            unsigned m = e0; int c = 0;
            if (e1 < m) { m = e1; c = 1; }
            if (e2 < m) { m = e2; c = 2; }
            if (e3 < m) { m = e3; c = 3; }
            int lcol = 4 * hh + c;
            unsigned hm = half_umin(m);
            unsigned vA = (unsigned)__builtin_amdgcn_readlane((int)hm, 31);
            unsigned vB = (unsigned)__builtin_amdgcn_readlane((int)hm, 63);
            unsigned vref = (lane < 32) ? vA : vB;
            unsigned long long msk = __ballot(m == vref);
            int laneA = __ffsll(msk & 0xFFFFFFFFull) - 1;
            int laneB = 32 + __ffsll(msk >> 32) - 1;
            int colA = __builtin_amdgcn_readlane(lcol, laneA);
            int colB = __builtin_amdgcn_readlane(lcol, laneB);
            unsigned long long keyA = ((unsigned long long)vA << 32) | (unsigned)((rA << 7) | colA);
            unsigned long long keyB = ((unsigned long long)vB << 32) | (unsigned)((rB << 7) | colB);
            if (lane == (rA >> 1)) { if (rA & 1) k1 = keyA; else k0 = keyA; }
            if (hasB && lane == (rB >> 1)) { if (rB & 1) k1 = keyB; else k0 = keyB; }
        }
    }

    szsE[r0] = s0;
    szsE[r1] = s1;
    __asm__ volatile("s_waitcnt lgkmcnt(0)" ::: "memory");
    if (lane == 0) {
        int c = 0;
        for (int i = 0; i < NPTS; ++i) rnk[i] = (szsE[i] > 0.f) ? c++ : -1;
    }
    __asm__ volatile("s_waitcnt lgkmcnt(0)" ::: "memory");
    out[b * NPTS + r0] = rnk[lab0];
    out[b * NPTS + r1] = rnk[lab1];
}

extern "C" void kernel_launch(void* const* d_in, const int* in_sizes, int n_in,
                              void* d_out, int out_size, void* d_ws, size_t ws_size,
                              hipStream_t stream) {
    const float* x  = (const float*)d_in[0];
    const float* W1 = (const float*)d_in[1];
    const float* b1 = (const float*)d_in[2];
    const float* W2 = (const float*)d_in[3];
    const float* b2 = (const float*)d_in[4];
    int* out = (int*)d_out;

    float* h = (float*)d_ws;                                   // 16.8 MB
    float* feats = h + (size_t)MROWS * H1;                     // 2.1 MB
    unsigned short* gxh = (unsigned short*)(feats + (size_t)MROWS * DOUT);
    unsigned short* gxl = gxh + (size_t)MROWS * DIN;           // 33.6 MB each
    unsigned short* gxq = gxl + (size_t)MROWS * DIN;
    unsigned short* wth = gxq + (size_t)MROWS * DIN;           // 0.52 MB each
    unsigned short* wtl = wth + (size_t)H1 * DIN;
    unsigned short* wtq = wtl + (size_t)H1 * DIN;

    const size_t need_mfma = ((size_t)MROWS * H1 + (size_t)MROWS * DOUT) * 4 +
                             (size_t)MROWS * DIN * 2 * 3 + (size_t)H1 * DIN * 2 * 3;

    if (ws_size >= need_mfma) {
        prep_kernel<<<2048, 256, 0, stream>>>(x, gxh, gxl, gxq, MROWS * DIN / 4);
        w1prep_kernel<<<64, 256, 0, stream>>>(W1, wth, wtl, wtq);
        mlp1_mfma<<<dim3(2, 256), 256, 0, stream>>>(
            (const f16*)gxh, (const f16*)gxl, (const f16*)gxq,
            (const f16*)wth, (const f16*)wtl, (const f16*)wtq, b1, h);
    } else {
        mlp1_kernel<<<dim3(4, 256), 256, 0, stream>>>(x, W1, b1, h);
    }
    mlp2_kernel<<<MROWS / 32, 256, 0, stream>>>(h, W2, b2, feats);
    ward_kernel<<<BB, 256, 0, stream>>>(feats, out);
}